// Round 1
// baseline (425.873 us; speedup 1.0000x reference)
//
#include <hip/hip_runtime.h>
#include <math.h>

// Problem constants (fixed by setup_inputs)
#define BB   256
#define DIN  2048
#define DD   512
#define CC   1000
#define NN   50000
#define FILTER_K 100
#define SLOT 512           // per-class capacity; max real ~90 old + <=256 new
#define CSTRIDE 16         // one counter per 64B cacheline (atomic contention)

#define SK1  16            // split-K for z = x@Wf  (klen 128)
#define SKP  8             // split-K for p = z@Wc^T (klen 64)
#define NBLK 512           // persistent grid: 2 blocks/CU, guaranteed resident

// ---------------- workspace layout (float elements) ----------------
#define Z_OFF     0                          // z:     [256][512]
#define CNT_OFF   (Z_OFF + BB*DD)            // cnt:   [1024*16] int (strided)
#define EI_OFF    (CNT_OFF + 1024*CSTRIDE)   // ei:    [1000][512] float2 (ent,idx)
#define WN_OFF    (EI_OFF + CC*SLOT*2)       // wn:    [1000][512]
#define ZP_OFF    (WN_OFF + CC*DD)           // zpart: [16][256][512]
#define PP_OFF    (ZP_OFF + SK1*BB*DD)       // ppart: [8][256][1000]

// barrier words live in the unused tail of the cnt region (classes use <16000)
#define BAR_CNT_IDX  (1008*CSTRIDE)
#define BAR_FLAG_IDX (1012*CSTRIDE)

#define SMEM_F 3712        // 14848 B shared overlay (max phase = class_weights 3588)

// ---- device-wide sense barrier (all NBLK blocks must be co-resident) ----
__device__ __forceinline__ void gsync(int* bcnt, int* bflag, int epoch) {
  __syncthreads();                      // drains vmcnt for all waves of block
  if (threadIdx.x == 0) {
    __threadfence();                    // agent release: wbL2 past non-coherent XCD L2
    int t = atomicAdd(bcnt, 1);         // device-scope RMW at coherent point
    if (t == epoch * NBLK - 1) {
      __hip_atomic_store(bflag, epoch, __ATOMIC_RELEASE, __HIP_MEMORY_SCOPE_AGENT);
    } else {
      while (__hip_atomic_load(bflag, __ATOMIC_ACQUIRE, __HIP_MEMORY_SCOPE_AGENT) < epoch)
        __builtin_amdgcn_s_sleep(4);    // ~256-cycle poll period
    }
    __threadfence();                    // agent acquire: invalidate stale L1/L2 lines
  }
  __syncthreads();
}

// ---- per-class select-K + normalized row-sum + column norm (verified body) ----
__device__ __forceinline__ void do_class(
    int c, int tid, float* smem, const float* supports_in, const float* z,
    const float2* ei, const int* cnt, float* wn) {
  int*   sel = (int*)smem;                       // [512]
  float* se  = smem + SLOT;                      // [512]
  int*   si  = (int*)(smem + 2*SLOT);            // [512]
  float (*part)[DD] = (float(*)[DD])(smem + 3*SLOT);  // [4][512]
  float* tot = smem + 3*SLOT + 4*DD;             // [4]
  const int lane = tid & 63, wid = tid >> 6;
  int n = cnt[c * CSTRIDE]; if (n > SLOT) n = SLOT;

  int seln;
  if (n <= FILTER_K) {
    seln = n;
    for (int i = tid; i < n; i += 256)
      sel[i] = __float_as_int(ei[(size_t)c * SLOT + i].y);
  } else {
    for (int i = tid; i < SLOT; i += 256) {
      if (i < n) {
        float2 pr = ei[(size_t)c * SLOT + i];
        se[i] = pr.x; si[i] = __float_as_int(pr.y);
      } else { se[i] = INFINITY; si[i] = 0x7fffffff; }
    }
    __syncthreads();
    for (int k = 2; k <= SLOT; k <<= 1)
      for (int j = k >> 1; j > 0; j >>= 1) {
        for (int i = tid; i < SLOT; i += 256) {
          int ixj = i ^ j;
          if (ixj > i) {
            bool up = ((i & k) == 0);
            float e1 = se[i], e2 = se[ixj];
            int i1 = si[i], i2 = si[ixj];
            bool gt = (e1 > e2) || (e1 == e2 && i1 > i2);
            if (gt == up) { se[i] = e2; se[ixj] = e1; si[i] = i2; si[ixj] = i1; }
          }
        }
        __syncthreads();
      }
    seln = FILTER_K;
    for (int i = tid; i < FILTER_K; i += 256) sel[i] = si[i];
  }
  __syncthreads();
  const int seln_pad = (seln + 15) & ~15;
  if (seln > 0)
    for (int i = seln + tid; i < seln_pad; i += 256) sel[i] = sel[0];
  __syncthreads();

  // lane owns dims [lane*8, lane*8+8); wave handles 4 rows per iteration
  float4 a0 = make_float4(0.f, 0.f, 0.f, 0.f), a1 = a0;
  for (int t = wid * 4; t < seln_pad; t += 16) {
    float4 u0[4], u1[4]; float s[4];
#pragma unroll
    for (int j = 0; j < 4; ++j) {
      int r = sel[t + j];
      const float4* p4 = (const float4*)((r < NN)
          ? supports_in + (size_t)r * DD : z + (size_t)(r - NN) * DD);
      u0[j] = p4[lane * 2]; u1[j] = p4[lane * 2 + 1];
    }
#pragma unroll
    for (int j = 0; j < 4; ++j)
      s[j] = u0[j].x * u0[j].x + u0[j].y * u0[j].y + u0[j].z * u0[j].z
           + u0[j].w * u0[j].w + u1[j].x * u1[j].x + u1[j].y * u1[j].y
           + u1[j].z * u1[j].z + u1[j].w * u1[j].w;
#pragma unroll
    for (int o = 1; o < 64; o <<= 1) {
#pragma unroll
      for (int j = 0; j < 4; ++j) s[j] += __shfl_xor(s[j], o, 64);
    }
#pragma unroll
    for (int j = 0; j < 4; ++j) {
      float sc = (t + j < seln) ? 1.0f / fmaxf(sqrtf(s[j]), 1e-12f) : 0.f;
      a0.x += u0[j].x * sc; a0.y += u0[j].y * sc;
      a0.z += u0[j].z * sc; a0.w += u0[j].w * sc;
      a1.x += u1[j].x * sc; a1.y += u1[j].y * sc;
      a1.z += u1[j].z * sc; a1.w += u1[j].w * sc;
    }
  }

  *(float4*)&part[wid][lane * 8] = a0;
  *(float4*)&part[wid][lane * 8 + 4] = a1;
  __syncthreads();
  const int d = tid * 2;
  float wx = part[0][d] + part[1][d] + part[2][d] + part[3][d];
  float wy = part[0][d + 1] + part[1][d + 1] + part[2][d + 1] + part[3][d + 1];
  float ss = wx * wx + wy * wy;
#pragma unroll
  for (int o = 1; o < 64; o <<= 1) ss += __shfl_xor(ss, o, 64);
  if (lane == 0) tot[wid] = ss;
  __syncthreads();
  float S = tot[0] + tot[1] + tot[2] + tot[3];
  float sc = 1.0f / fmaxf(sqrtf(S), 1e-12f);
  ((float2*)(wn + (size_t)c * DD))[tid] = make_float2(wx * sc, wy * sc);
}

// =================== the persistent mega-kernel ===================
__global__ __launch_bounds__(256, 2) void mega(
    const float* x, const float* Wf, const float* Wc, const float* bc,
    const float* supports_in, const float* ent_in, const int* labels_idx,
    float* out, float* ws) {
  __shared__ __align__(16) float smem[SMEM_F];
  float*  z     = ws + Z_OFF;
  int*    cnt   = (int*)(ws + CNT_OFF);
  float2* ei    = (float2*)(ws + EI_OFF);
  float*  wn    = ws + WN_OFF;
  float*  zpart = ws + ZP_OFF;
  float*  ppart = ws + PP_OFF;
  int* bar_cnt  = cnt + BAR_CNT_IDX;
  int* bar_flag = cnt + BAR_FLAG_IDX;
  const int bid = blockIdx.x, tid = threadIdx.x;

  // ---- Phase 1: zpart = x@Wf split-K (blocks 0..255) | old-row scatter (256..451)
  if (bid < 256) {
    // 64x128 tile, 4x8 micro, BK=16, klen=128 (SK1=16)
    float (*As)[68]  = (float(*)[68])smem;
    float (*Bs)[132] = (float(*)[132])(smem + 16 * 68);
    const int m0 = ((bid >> 2) & 3) * 64;
    const int n0 = (bid & 3) * 128;
    const int k0 = (bid >> 4) * 128;
    const int ar = tid >> 2, ac = (tid & 3) * 4;
    const int br = tid >> 4, bcn = (tid & 15) * 8;
    const int tm = (tid >> 4) * 4, tn = (tid & 15) * 4;
    float acc[4][8] = {};
    float4 av  = *(const float4*)&x[(size_t)(m0 + ar) * DIN + k0 + ac];
    float4 bv0 = *(const float4*)&Wf[(size_t)(k0 + br) * DD + n0 + bcn];
    float4 bv1 = *(const float4*)&Wf[(size_t)(k0 + br) * DD + n0 + bcn + 4];
    for (int kk = 0; kk < 128; kk += 16) {
      __syncthreads();
      As[ac + 0][ar] = av.x; As[ac + 1][ar] = av.y;
      As[ac + 2][ar] = av.z; As[ac + 3][ar] = av.w;
      *(float4*)&Bs[br][bcn] = bv0;
      *(float4*)&Bs[br][bcn + 4] = bv1;
      __syncthreads();
      if (kk + 16 < 128) {   // register prefetch of next K-tile
        av  = *(const float4*)&x[(size_t)(m0 + ar) * DIN + k0 + kk + 16 + ac];
        bv0 = *(const float4*)&Wf[(size_t)(k0 + kk + 16 + br) * DD + n0 + bcn];
        bv1 = *(const float4*)&Wf[(size_t)(k0 + kk + 16 + br) * DD + n0 + bcn + 4];
      }
#pragma unroll
      for (int q = 0; q < 16; ++q) {
        float4 a  = *(const float4*)&As[q][tm];
        float4 b0 = *(const float4*)&Bs[q][tn];
        float4 b1 = *(const float4*)&Bs[q][tn + 64];
        float aa[4] = {a.x, a.y, a.z, a.w};
        float bb[8] = {b0.x, b0.y, b0.z, b0.w, b1.x, b1.y, b1.z, b1.w};
#pragma unroll
        for (int i = 0; i < 4; ++i)
#pragma unroll
          for (int j = 0; j < 8; ++j) acc[i][j] += aa[i] * bb[j];
      }
    }
    float* Cb = zpart + (size_t)(bid >> 4) * BB * DD;
#pragma unroll
    for (int i = 0; i < 4; ++i) {
      *(float4*)&Cb[(size_t)(m0 + tm + i) * DD + n0 + tn] =
          make_float4(acc[i][0], acc[i][1], acc[i][2], acc[i][3]);
      *(float4*)&Cb[(size_t)(m0 + tm + i) * DD + n0 + 64 + tn] =
          make_float4(acc[i][4], acc[i][5], acc[i][6], acc[i][7]);
    }
  } else if (bid < 452) {
    int m = (bid - 256) * 256 + tid;
    if (m < NN) {
      int c = labels_idx[m];
      int pos = atomicAdd(&cnt[c * CSTRIDE], 1);
      if (pos < SLOT) {
        float2 pr; pr.x = ent_in[m]; pr.y = __int_as_float(m);
        ei[(size_t)c * SLOT + pos] = pr;
      }
    }
  }
  gsync(bar_cnt, bar_flag, 1);

  // ---- Phase 2: z = sum of 16 split-K partials (blocks 0..127) ----
  {
    const int n4 = BB * DD / 4;
    int i = bid * 256 + tid;
    if (i < n4) {
      const float4* p4 = (const float4*)zpart;
      float4 a = p4[i];
#pragma unroll
      for (int s = 1; s < SK1; ++s) {
        float4 b = p4[(size_t)s * n4 + i];
        a.x += b.x; a.y += b.y; a.z += b.z; a.w += b.w;
      }
      ((float4*)z)[i] = a;
    }
  }
  gsync(bar_cnt, bar_flag, 2);

  // ---- Phase 3: ppart[s] = z @ Wc^T (all 512 blocks; 64x64 tile, klen 64) ----
  {
    float (*As)[68] = (float(*)[68])smem;
    float (*Bs)[68] = (float(*)[68])(smem + 16 * 68);
    const int n0 = (bid & 15) * 64;
    const int m0 = ((bid >> 4) & 3) * 64;
    const int ks = bid >> 6;            // 0..7
    const int k0 = ks * 64;
    const int ar = tid >> 2, ac = (tid & 3) * 4;
    const int tm = (tid >> 4) * 4, tn = (tid & 15) * 4;
    float acc[4][4] = {};
    float4 av = *(const float4*)&z[(size_t)(m0 + ar) * DD + k0 + ac];
    float4 bv = make_float4(0.f, 0.f, 0.f, 0.f);
    if (n0 + ar < CC) bv = *(const float4*)&Wc[(size_t)(n0 + ar) * DD + k0 + ac];
    for (int kk = 0; kk < 64; kk += 16) {
      __syncthreads();
      As[ac + 0][ar] = av.x; As[ac + 1][ar] = av.y;
      As[ac + 2][ar] = av.z; As[ac + 3][ar] = av.w;
      Bs[ac + 0][ar] = bv.x; Bs[ac + 1][ar] = bv.y;
      Bs[ac + 2][ar] = bv.z; Bs[ac + 3][ar] = bv.w;
      __syncthreads();
      if (kk + 16 < 64) {
        av = *(const float4*)&z[(size_t)(m0 + ar) * DD + k0 + kk + 16 + ac];
        if (n0 + ar < CC)
          bv = *(const float4*)&Wc[(size_t)(n0 + ar) * DD + k0 + kk + 16 + ac];
      }
#pragma unroll
      for (int q = 0; q < 16; ++q) {
        float4 a = *(const float4*)&As[q][tm];
        float4 b = *(const float4*)&Bs[q][tn];
        float aa[4] = {a.x, a.y, a.z, a.w};
        float bb[4] = {b.x, b.y, b.z, b.w};
#pragma unroll
        for (int i = 0; i < 4; ++i)
#pragma unroll
          for (int j = 0; j < 4; ++j) acc[i][j] += aa[i] * bb[j];
      }
    }
    float* Cb = ppart + (size_t)ks * BB * CC;
#pragma unroll
    for (int i = 0; i < 4; ++i) {
      int n = n0 + tn;
      if (n + 3 < CC) {
        *(float4*)&Cb[(size_t)(m0 + tm + i) * CC + n] =
            make_float4(acc[i][0], acc[i][1], acc[i][2], acc[i][3]);
      } else {
#pragma unroll
        for (int j = 0; j < 4; ++j)
          if (n + j < CC) Cb[(size_t)(m0 + tm + i) * CC + n + j] = acc[i][j];
      }
    }
  }
  gsync(bar_cnt, bar_flag, 3);

  // ---- Phase 4: rowstats — argmax+entropy over p partials; new-row scatter ----
  if (bid < BB) {
    float* smv = smem; int* smi = (int*)(smem + 4);
    float* ssm = smem + 8; float* tsm = smem + 12;
    const int b = bid;
    const int lane = tid & 63, wid = tid >> 6;
    float r[4];
    float mv = -INFINITY; int mi = 0x7fffffff;
#pragma unroll
    for (int i = 0; i < 4; ++i) {
      int c = tid + 256 * i;
      if (c < CC) {
        float v = bc[c];
#pragma unroll
        for (int s = 0; s < SKP; ++s)
          v += ppart[(size_t)s * BB * CC + (size_t)b * CC + c];
        r[i] = v;
      } else r[i] = -INFINITY;
      if (r[i] > mv) { mv = r[i]; mi = c; }
    }
#pragma unroll
    for (int o = 32; o > 0; o >>= 1) {
      float ov = __shfl_down(mv, o, 64);
      int oi = __shfl_down(mi, o, 64);
      if (ov > mv || (ov == mv && oi < mi)) { mv = ov; mi = oi; }
    }
    if (lane == 0) { smv[wid] = mv; smi[wid] = mi; }
    __syncthreads();
    if (tid == 0) {
#pragma unroll
      for (int w = 1; w < 4; ++w)
        if (smv[w] > smv[0] || (smv[w] == smv[0] && smi[w] < smi[0])) {
          smv[0] = smv[w]; smi[0] = smi[w];
        }
    }
    __syncthreads();
    const float m = smv[0]; const int am = smi[0];
    float s = 0.f, t = 0.f;
#pragma unroll
    for (int i = 0; i < 4; ++i) {
      if (tid + 256 * i < CC) {
        float u = r[i] - m;
        float e = expf(u);
        s += e; t += u * e;
      }
    }
#pragma unroll
    for (int o = 32; o > 0; o >>= 1) {
      s += __shfl_down(s, o, 64);
      t += __shfl_down(t, o, 64);
    }
    if (lane == 0) { ssm[wid] = s; tsm[wid] = t; }
    __syncthreads();
    if (tid == 0) {
      float S = ssm[0] + ssm[1] + ssm[2] + ssm[3];
      float T = tsm[0] + tsm[1] + tsm[2] + tsm[3];
      float ent = logf(S) - T / S;
      int pos = atomicAdd(&cnt[am * CSTRIDE], 1);
      if (pos < SLOT) {
        float2 pr; pr.x = ent; pr.y = __int_as_float(NN + b);
        ei[(size_t)am * SLOT + pos] = pr;
      }
    }
  }
  gsync(bar_cnt, bar_flag, 4);

  // ---- Phase 5: class weights (each block: class bid, then bid+512) ----
  do_class(bid, tid, smem, supports_in, z, ei, cnt, wn);
  __syncthreads();
  if (bid + 512 < CC)
    do_class(bid + 512, tid, smem, supports_in, z, ei, cnt, wn);
  gsync(bar_cnt, bar_flag, 5);

  // ---- Phase 6: out = z @ wn^T (blocks 0..255; 16x64 tile, full K=512) ----
  if (bid < 256) {
    float (*As)[20] = (float(*)[20])smem;           // [k][row]
    float (*Bs)[68] = (float(*)[68])(smem + 16 * 20);
    const int m0 = (bid >> 4) * 16;
    const int n0 = (bid & 15) * 64;
    const int arow = tid >> 4, ak = tid & 15;
    const int br = tid >> 2, bcl = (tid & 3) * 4;
    const int tr = tid >> 4, tn4 = (tid & 15) * 4;
    float acc[4] = {};
    float av = z[(size_t)(m0 + arow) * DD + ak];
    float4 bv = make_float4(0.f, 0.f, 0.f, 0.f);
    if (n0 + br < CC) bv = *(const float4*)&wn[(size_t)(n0 + br) * DD + bcl];
    for (int k0 = 0; k0 < DD; k0 += 16) {
      __syncthreads();
      As[ak][arow] = av;
      Bs[bcl + 0][br] = bv.x; Bs[bcl + 1][br] = bv.y;
      Bs[bcl + 2][br] = bv.z; Bs[bcl + 3][br] = bv.w;
      __syncthreads();
      if (k0 + 16 < DD) {
        av = z[(size_t)(m0 + arow) * DD + k0 + 16 + ak];
        if (n0 + br < CC)
          bv = *(const float4*)&wn[(size_t)(n0 + br) * DD + k0 + 16 + bcl];
      }
#pragma unroll
      for (int q = 0; q < 16; ++q) {
        float a = As[q][tr];
        float4 b = *(const float4*)&Bs[q][tn4];
        acc[0] += a * b.x; acc[1] += a * b.y;
        acc[2] += a * b.z; acc[3] += a * b.w;
      }
    }
    int n = n0 + tn4;
    if (n + 3 < CC) {
      *(float4*)&out[(size_t)(m0 + tr) * CC + n] =
          make_float4(acc[0], acc[1], acc[2], acc[3]);
    } else {
#pragma unroll
      for (int j = 0; j < 4; ++j)
        if (n + j < CC) out[(size_t)(m0 + tr) * CC + n + j] = acc[j];
    }
  }
}

// ============================ launcher ===================================
extern "C" void kernel_launch(void* const* d_in, const int* in_sizes, int n_in,
                              void* d_out, int out_size, void* d_ws, size_t ws_size,
                              hipStream_t stream) {
  (void)in_sizes; (void)n_in; (void)out_size; (void)ws_size;
  const float* x           = (const float*)d_in[0];
  const float* Wf          = (const float*)d_in[1];
  const float* Wc          = (const float*)d_in[2];
  const float* bc          = (const float*)d_in[3];
  const float* supports_in = (const float*)d_in[4];
  const float* ent_in      = (const float*)d_in[5];
  const int*   labels_idx  = (const int*)d_in[6];
  float* out = (float*)d_out;
  float* W = (float*)d_ws;
  int* cnt = (int*)(W + CNT_OFF);

  // zero class counters + barrier words (64 KB, covers idx 0..16383)
  hipMemsetAsync(cnt, 0, 1024 * CSTRIDE * sizeof(int), stream);
  // single persistent kernel; 512 blocks = 2/CU guaranteed resident
  hipLaunchKernelGGL(mega, dim3(NBLK), dim3(256), 0, stream,
                     x, Wf, Wc, bc, supports_in, ent_in, labels_idx, out, W);
}

// Round 2
// 329.940 us; speedup vs baseline: 1.2908x; 1.2908x over previous
//
#include <hip/hip_runtime.h>
#include <math.h>

// Problem constants (fixed by setup_inputs)
#define BB   256
#define DIN  2048
#define DD   512
#define CC   1000
#define NN   50000
#define FILTER_K 100
#define SLOT 512           // per-class capacity; max real ~90 old + <=256 new
#define CSTRIDE 16         // one counter per 64B cacheline (atomic contention)

#define SK1  32            // split-K for z = x@Wf  (klen 64)
#define SKP  8             // split-K for p = z@Wc^T (klen 64)
#define NBLK 512           // persistent grid: 2 blocks/CU, guaranteed resident

// ---------------- workspace layout (float elements) ----------------
#define Z_OFF     0                          // z:     [256][512]
#define CNT_OFF   (Z_OFF + BB*DD)            // cnt:   [1024*16] int (strided)
#define EI_OFF    (CNT_OFF + 1024*CSTRIDE)   // ei:    [1000][512] float2 (ent,idx)
#define WN_OFF    (EI_OFF + CC*SLOT*2)       // wn:    [1000][512]
#define ZP_OFF    (WN_OFF + CC*DD)           // zpart: [32][256][512]
#define PP_OFF    (ZP_OFF + SK1*BB*DD)       // ppart: [8][256][1000]

// barrier words live in the unused tail of the cnt region (classes use <16000)
#define BAR_CNT_IDX  (1008*CSTRIDE)
#define BAR_FLAG_IDX (1012*CSTRIDE)

#define SMEM_F 3712        // 14848 B shared overlay (max phase = class_weights 3588)

// ---- device-wide sense barrier (all NBLK blocks must be co-resident) ----
// RELAXED polling: agent-scope relaxed atomic load compiles to a coherent
// (sc1) load WITHOUT the per-iteration buffer_inv that ACQUIRE emits.
// Acquire/release semantics are hoisted to ONE __threadfence on each side.
__device__ __forceinline__ void gsync(int* bcnt, int* bflag, int epoch) {
  __syncthreads();                      // all waves of block done with phase
  if (threadIdx.x == 0) {
    __threadfence();                    // release: waitcnt + wbL2 once
    int t = __hip_atomic_fetch_add(bcnt, 1, __ATOMIC_RELAXED,
                                   __HIP_MEMORY_SCOPE_AGENT);
    if (t == epoch * NBLK - 1) {
      __hip_atomic_store(bflag, epoch, __ATOMIC_RELAXED,
                         __HIP_MEMORY_SCOPE_AGENT);
    } else {
      while (__hip_atomic_load(bflag, __ATOMIC_RELAXED,
                               __HIP_MEMORY_SCOPE_AGENT) < epoch)
        __builtin_amdgcn_s_sleep(8);    // ~512-cycle poll period
    }
    __threadfence();                    // acquire: buffer_inv once
  }
  __syncthreads();
}

// ---- per-class select-K + normalized row-sum + column norm (verified body) ----
__device__ __forceinline__ void do_class(
    int c, int tid, float* smem, const float* supports_in, const float* z,
    const float2* ei, const int* cnt, float* wn) {
  int*   sel = (int*)smem;                       // [512]
  float* se  = smem + SLOT;                      // [512]
  int*   si  = (int*)(smem + 2*SLOT);            // [512]
  float (*part)[DD] = (float(*)[DD])(smem + 3*SLOT);  // [4][512]
  float* tot = smem + 3*SLOT + 4*DD;             // [4]
  const int lane = tid & 63, wid = tid >> 6;
  int n = cnt[c * CSTRIDE]; if (n > SLOT) n = SLOT;

  int seln;
  if (n <= FILTER_K) {
    seln = n;
    for (int i = tid; i < n; i += 256)
      sel[i] = __float_as_int(ei[(size_t)c * SLOT + i].y);
  } else {
    for (int i = tid; i < SLOT; i += 256) {
      if (i < n) {
        float2 pr = ei[(size_t)c * SLOT + i];
        se[i] = pr.x; si[i] = __float_as_int(pr.y);
      } else { se[i] = INFINITY; si[i] = 0x7fffffff; }
    }
    __syncthreads();
    for (int k = 2; k <= SLOT; k <<= 1)
      for (int j = k >> 1; j > 0; j >>= 1) {
        for (int i = tid; i < SLOT; i += 256) {
          int ixj = i ^ j;
          if (ixj > i) {
            bool up = ((i & k) == 0);
            float e1 = se[i], e2 = se[ixj];
            int i1 = si[i], i2 = si[ixj];
            bool gt = (e1 > e2) || (e1 == e2 && i1 > i2);
            if (gt == up) { se[i] = e2; se[ixj] = e1; si[i] = i2; si[ixj] = i1; }
          }
        }
        __syncthreads();
      }
    seln = FILTER_K;
    for (int i = tid; i < FILTER_K; i += 256) sel[i] = si[i];
  }
  __syncthreads();
  const int seln_pad = (seln + 15) & ~15;
  if (seln > 0)
    for (int i = seln + tid; i < seln_pad; i += 256) sel[i] = sel[0];
  __syncthreads();

  // lane owns dims [lane*8, lane*8+8); wave handles 4 rows per iteration
  float4 a0 = make_float4(0.f, 0.f, 0.f, 0.f), a1 = a0;
  for (int t = wid * 4; t < seln_pad; t += 16) {
    float4 u0[4], u1[4]; float s[4];
#pragma unroll
    for (int j = 0; j < 4; ++j) {
      int r = sel[t + j];
      const float4* p4 = (const float4*)((r < NN)
          ? supports_in + (size_t)r * DD : z + (size_t)(r - NN) * DD);
      u0[j] = p4[lane * 2]; u1[j] = p4[lane * 2 + 1];
    }
#pragma unroll
    for (int j = 0; j < 4; ++j)
      s[j] = u0[j].x * u0[j].x + u0[j].y * u0[j].y + u0[j].z * u0[j].z
           + u0[j].w * u0[j].w + u1[j].x * u1[j].x + u1[j].y * u1[j].y
           + u1[j].z * u1[j].z + u1[j].w * u1[j].w;
#pragma unroll
    for (int o = 1; o < 64; o <<= 1) {
#pragma unroll
      for (int j = 0; j < 4; ++j) s[j] += __shfl_xor(s[j], o, 64);
    }
#pragma unroll
    for (int j = 0; j < 4; ++j) {
      float sc = (t + j < seln) ? 1.0f / fmaxf(sqrtf(s[j]), 1e-12f) : 0.f;
      a0.x += u0[j].x * sc; a0.y += u0[j].y * sc;
      a0.z += u0[j].z * sc; a0.w += u0[j].w * sc;
      a1.x += u1[j].x * sc; a1.y += u1[j].y * sc;
      a1.z += u1[j].z * sc; a1.w += u1[j].w * sc;
    }
  }

  *(float4*)&part[wid][lane * 8] = a0;
  *(float4*)&part[wid][lane * 8 + 4] = a1;
  __syncthreads();
  const int d = tid * 2;
  float wx = part[0][d] + part[1][d] + part[2][d] + part[3][d];
  float wy = part[0][d + 1] + part[1][d + 1] + part[2][d + 1] + part[3][d + 1];
  float ss = wx * wx + wy * wy;
#pragma unroll
  for (int o = 1; o < 64; o <<= 1) ss += __shfl_xor(ss, o, 64);
  if (lane == 0) tot[wid] = ss;
  __syncthreads();
  float S = tot[0] + tot[1] + tot[2] + tot[3];
  float sc = 1.0f / fmaxf(sqrtf(S), 1e-12f);
  ((float2*)(wn + (size_t)c * DD))[tid] = make_float2(wx * sc, wy * sc);
}

// =================== the persistent mega-kernel ===================
__global__ __launch_bounds__(256, 2) void mega(
    const float* x, const float* Wf, const float* Wc, const float* bc,
    const float* supports_in, const float* ent_in, const int* labels_idx,
    float* out, float* ws) {
  __shared__ __align__(16) float smem[SMEM_F];
  float*  z     = ws + Z_OFF;
  int*    cnt   = (int*)(ws + CNT_OFF);
  float2* ei    = (float2*)(ws + EI_OFF);
  float*  wn    = ws + WN_OFF;
  float*  zpart = ws + ZP_OFF;
  float*  ppart = ws + PP_OFF;
  int* bar_cnt  = cnt + BAR_CNT_IDX;
  int* bar_flag = cnt + BAR_FLAG_IDX;
  const int bid = blockIdx.x, tid = threadIdx.x;

  // ---- Phase 1: zpart = x@Wf split-K, ALL 512 blocks (SK1=32, klen=64) ----
  {
    float (*As)[68]  = (float(*)[68])smem;
    float (*Bs)[132] = (float(*)[132])(smem + 16 * 68);
    const int m0 = ((bid >> 2) & 3) * 64;
    const int n0 = (bid & 3) * 128;
    const int k0 = (bid >> 4) * 64;
    const int ar = tid >> 2, ac = (tid & 3) * 4;
    const int br = tid >> 4, bcn = (tid & 15) * 8;
    const int tm = (tid >> 4) * 4, tn = (tid & 15) * 4;
    float acc[4][8] = {};
    float4 av  = *(const float4*)&x[(size_t)(m0 + ar) * DIN + k0 + ac];
    float4 bv0 = *(const float4*)&Wf[(size_t)(k0 + br) * DD + n0 + bcn];
    float4 bv1 = *(const float4*)&Wf[(size_t)(k0 + br) * DD + n0 + bcn + 4];
    for (int kk = 0; kk < 64; kk += 16) {
      __syncthreads();
      As[ac + 0][ar] = av.x; As[ac + 1][ar] = av.y;
      As[ac + 2][ar] = av.z; As[ac + 3][ar] = av.w;
      *(float4*)&Bs[br][bcn] = bv0;
      *(float4*)&Bs[br][bcn + 4] = bv1;
      __syncthreads();
      if (kk + 16 < 64) {   // register prefetch of next K-tile
        av  = *(const float4*)&x[(size_t)(m0 + ar) * DIN + k0 + kk + 16 + ac];
        bv0 = *(const float4*)&Wf[(size_t)(k0 + kk + 16 + br) * DD + n0 + bcn];
        bv1 = *(const float4*)&Wf[(size_t)(k0 + kk + 16 + br) * DD + n0 + bcn + 4];
      }
#pragma unroll
      for (int q = 0; q < 16; ++q) {
        float4 a  = *(const float4*)&As[q][tm];
        float4 b0 = *(const float4*)&Bs[q][tn];
        float4 b1 = *(const float4*)&Bs[q][tn + 64];
        float aa[4] = {a.x, a.y, a.z, a.w};
        float bb[8] = {b0.x, b0.y, b0.z, b0.w, b1.x, b1.y, b1.z, b1.w};
#pragma unroll
        for (int i = 0; i < 4; ++i)
#pragma unroll
          for (int j = 0; j < 8; ++j) acc[i][j] += aa[i] * bb[j];
      }
    }
    float* Cb = zpart + (size_t)(bid >> 4) * BB * DD;
#pragma unroll
    for (int i = 0; i < 4; ++i) {
      *(float4*)&Cb[(size_t)(m0 + tm + i) * DD + n0 + tn] =
          make_float4(acc[i][0], acc[i][1], acc[i][2], acc[i][3]);
      *(float4*)&Cb[(size_t)(m0 + tm + i) * DD + n0 + 64 + tn] =
          make_float4(acc[i][4], acc[i][5], acc[i][6], acc[i][7]);
    }
  }
  gsync(bar_cnt, bar_flag, 1);

  // ---- Phase 2: z = sum of 32 partials (blocks 0..127) | old-row scatter
  // ---- (blocks 128..323); remaining blocks idle through the barrier. ----
  if (bid < 128) {
    const int n4 = BB * DD / 4;
    int i = bid * 256 + tid;
    if (i < n4) {
      const float4* p4 = (const float4*)zpart;
      float4 a = p4[i];
#pragma unroll
      for (int s = 1; s < SK1; ++s) {
        float4 b = p4[(size_t)s * n4 + i];
        a.x += b.x; a.y += b.y; a.z += b.z; a.w += b.w;
      }
      ((float4*)z)[i] = a;
    }
  } else if (bid < 324) {
    int m = (bid - 128) * 256 + tid;
    if (m < NN) {
      int c = labels_idx[m];
      int pos = atomicAdd(&cnt[c * CSTRIDE], 1);
      if (pos < SLOT) {
        float2 pr; pr.x = ent_in[m]; pr.y = __int_as_float(m);
        ei[(size_t)c * SLOT + pos] = pr;
      }
    }
  }
  gsync(bar_cnt, bar_flag, 2);

  // ---- Phase 3: ppart[s] = z @ Wc^T (all 512 blocks; 64x64 tile, klen 64) ----
  {
    float (*As)[68] = (float(*)[68])smem;
    float (*Bs)[68] = (float(*)[68])(smem + 16 * 68);
    const int n0 = (bid & 15) * 64;
    const int m0 = ((bid >> 4) & 3) * 64;
    const int ks = bid >> 6;            // 0..7
    const int k0 = ks * 64;
    const int ar = tid >> 2, ac = (tid & 3) * 4;
    const int tm = (tid >> 4) * 4, tn = (tid & 15) * 4;
    float acc[4][4] = {};
    float4 av = *(const float4*)&z[(size_t)(m0 + ar) * DD + k0 + ac];
    float4 bv = make_float4(0.f, 0.f, 0.f, 0.f);
    if (n0 + ar < CC) bv = *(const float4*)&Wc[(size_t)(n0 + ar) * DD + k0 + ac];
    for (int kk = 0; kk < 64; kk += 16) {
      __syncthreads();
      As[ac + 0][ar] = av.x; As[ac + 1][ar] = av.y;
      As[ac + 2][ar] = av.z; As[ac + 3][ar] = av.w;
      Bs[ac + 0][ar] = bv.x; Bs[ac + 1][ar] = bv.y;
      Bs[ac + 2][ar] = bv.z; Bs[ac + 3][ar] = bv.w;
      __syncthreads();
      if (kk + 16 < 64) {
        av = *(const float4*)&z[(size_t)(m0 + ar) * DD + k0 + kk + 16 + ac];
        if (n0 + ar < CC)
          bv = *(const float4*)&Wc[(size_t)(n0 + ar) * DD + k0 + kk + 16 + ac];
      }
#pragma unroll
      for (int q = 0; q < 16; ++q) {
        float4 a = *(const float4*)&As[q][tm];
        float4 b = *(const float4*)&Bs[q][tn];
        float aa[4] = {a.x, a.y, a.z, a.w};
        float bb[4] = {b.x, b.y, b.z, b.w};
#pragma unroll
        for (int i = 0; i < 4; ++i)
#pragma unroll
          for (int j = 0; j < 4; ++j) acc[i][j] += aa[i] * bb[j];
      }
    }
    float* Cb = ppart + (size_t)ks * BB * CC;
#pragma unroll
    for (int i = 0; i < 4; ++i) {
      int n = n0 + tn;
      if (n + 3 < CC) {
        *(float4*)&Cb[(size_t)(m0 + tm + i) * CC + n] =
            make_float4(acc[i][0], acc[i][1], acc[i][2], acc[i][3]);
      } else {
#pragma unroll
        for (int j = 0; j < 4; ++j)
          if (n + j < CC) Cb[(size_t)(m0 + tm + i) * CC + n + j] = acc[i][j];
      }
    }
  }
  gsync(bar_cnt, bar_flag, 3);

  // ---- Phase 4: rowstats — argmax+entropy over p partials; new-row scatter ----
  if (bid < BB) {
    float* smv = smem; int* smi = (int*)(smem + 4);
    float* ssm = smem + 8; float* tsm = smem + 12;
    const int b = bid;
    const int lane = tid & 63, wid = tid >> 6;
    float r[4];
    float mv = -INFINITY; int mi = 0x7fffffff;
#pragma unroll
    for (int i = 0; i < 4; ++i) {
      int c = tid + 256 * i;
      if (c < CC) {
        float v = bc[c];
#pragma unroll
        for (int s = 0; s < SKP; ++s)
          v += ppart[(size_t)s * BB * CC + (size_t)b * CC + c];
        r[i] = v;
      } else r[i] = -INFINITY;
      if (r[i] > mv) { mv = r[i]; mi = c; }
    }
#pragma unroll
    for (int o = 32; o > 0; o >>= 1) {
      float ov = __shfl_down(mv, o, 64);
      int oi = __shfl_down(mi, o, 64);
      if (ov > mv || (ov == mv && oi < mi)) { mv = ov; mi = oi; }
    }
    if (lane == 0) { smv[wid] = mv; smi[wid] = mi; }
    __syncthreads();
    if (tid == 0) {
#pragma unroll
      for (int w = 1; w < 4; ++w)
        if (smv[w] > smv[0] || (smv[w] == smv[0] && smi[w] < smi[0])) {
          smv[0] = smv[w]; smi[0] = smi[w];
        }
    }
    __syncthreads();
    const float m = smv[0]; const int am = smi[0];
    float s = 0.f, t = 0.f;
#pragma unroll
    for (int i = 0; i < 4; ++i) {
      if (tid + 256 * i < CC) {
        float u = r[i] - m;
        float e = expf(u);
        s += e; t += u * e;
      }
    }
#pragma unroll
    for (int o = 32; o > 0; o >>= 1) {
      s += __shfl_down(s, o, 64);
      t += __shfl_down(t, o, 64);
    }
    if (lane == 0) { ssm[wid] = s; tsm[wid] = t; }
    __syncthreads();
    if (tid == 0) {
      float S = ssm[0] + ssm[1] + ssm[2] + ssm[3];
      float T = tsm[0] + tsm[1] + tsm[2] + tsm[3];
      float ent = logf(S) - T / S;
      int pos = atomicAdd(&cnt[am * CSTRIDE], 1);
      if (pos < SLOT) {
        float2 pr; pr.x = ent; pr.y = __int_as_float(NN + b);
        ei[(size_t)am * SLOT + pos] = pr;
      }
    }
  }
  gsync(bar_cnt, bar_flag, 4);

  // ---- Phase 5: class weights (each block: class bid, then bid+512) ----
  do_class(bid, tid, smem, supports_in, z, ei, cnt, wn);
  __syncthreads();
  if (bid + 512 < CC)
    do_class(bid + 512, tid, smem, supports_in, z, ei, cnt, wn);
  gsync(bar_cnt, bar_flag, 5);

  // ---- Phase 6: out = z @ wn^T (blocks 0..255; 16x64 tile, full K=512) ----
  if (bid < 256) {
    float (*As)[20] = (float(*)[20])smem;           // [k][row]
    float (*Bs)[68] = (float(*)[68])(smem + 16 * 20);
    const int m0 = (bid >> 4) * 16;
    const int n0 = (bid & 15) * 64;
    const int arow = tid >> 4, ak = tid & 15;
    const int br = tid >> 2, bcl = (tid & 3) * 4;
    const int tr = tid >> 4, tn4 = (tid & 15) * 4;
    float acc[4] = {};
    float av = z[(size_t)(m0 + arow) * DD + ak];
    float4 bv = make_float4(0.f, 0.f, 0.f, 0.f);
    if (n0 + br < CC) bv = *(const float4*)&wn[(size_t)(n0 + br) * DD + bcl];
    for (int k0 = 0; k0 < DD; k0 += 16) {
      __syncthreads();
      As[ak][arow] = av;
      Bs[bcl + 0][br] = bv.x; Bs[bcl + 1][br] = bv.y;
      Bs[bcl + 2][br] = bv.z; Bs[bcl + 3][br] = bv.w;
      __syncthreads();
      if (k0 + 16 < DD) {
        av = z[(size_t)(m0 + arow) * DD + k0 + 16 + ak];
        if (n0 + br < CC)
          bv = *(const float4*)&wn[(size_t)(n0 + br) * DD + k0 + 16 + bcl];
      }
#pragma unroll
      for (int q = 0; q < 16; ++q) {
        float a = As[q][tr];
        float4 b = *(const float4*)&Bs[q][tn4];
        acc[0] += a * b.x; acc[1] += a * b.y;
        acc[2] += a * b.z; acc[3] += a * b.w;
      }
    }
    int n = n0 + tn4;
    if (n + 3 < CC) {
      *(float4*)&out[(size_t)(m0 + tr) * CC + n] =
          make_float4(acc[0], acc[1], acc[2], acc[3]);
    } else {
#pragma unroll
      for (int j = 0; j < 4; ++j)
        if (n + j < CC) out[(size_t)(m0 + tr) * CC + n + j] = acc[j];
    }
  }
}

// ============================ launcher ===================================
extern "C" void kernel_launch(void* const* d_in, const int* in_sizes, int n_in,
                              void* d_out, int out_size, void* d_ws, size_t ws_size,
                              hipStream_t stream) {
  (void)in_sizes; (void)n_in; (void)out_size; (void)ws_size;
  const float* x           = (const float*)d_in[0];
  const float* Wf          = (const float*)d_in[1];
  const float* Wc          = (const float*)d_in[2];
  const float* bc          = (const float*)d_in[3];
  const float* supports_in = (const float*)d_in[4];
  const float* ent_in      = (const float*)d_in[5];
  const int*   labels_idx  = (const int*)d_in[6];
  float* out = (float*)d_out;
  float* W = (float*)d_ws;
  int* cnt = (int*)(W + CNT_OFF);

  // zero class counters + barrier words (64 KB, covers idx 0..16383)
  hipMemsetAsync(cnt, 0, 1024 * CSTRIDE * sizeof(int), stream);
  // single persistent kernel; 512 blocks = 2/CU guaranteed resident
  hipLaunchKernelGGL(mega, dim3(NBLK), dim3(256), 0, stream,
                     x, Wf, Wc, bc, supports_in, ent_in, labels_idx, out, W);
}

// Round 3
// 228.671 us; speedup vs baseline: 1.8624x; 1.4429x over previous
//
#include <hip/hip_runtime.h>
#include <math.h>

// Problem constants (fixed by setup_inputs)
#define BB   256
#define DIN  2048
#define DD   512
#define CC   1000
#define NN   50000
#define FILTER_K 100
#define SLOT 512           // per-class capacity; max real ~90 old + <=256 new
#define CSTRIDE 16         // one counter per 64B cacheline (atomic contention)

#define SK1  32            // split-K for z = x@Wf  (klen 64)
#define SKP  8             // split-K for p = z@Wc^T (klen 64)
#define NBLK 512           // persistent grid: 2 blocks/CU, guaranteed resident

// ---------------- workspace layout (float elements) ----------------
#define Z_OFF     0                          // z:     [256][512]
#define CNT_OFF   (Z_OFF + BB*DD)            // cnt:   [1024*16] int (strided)
#define EI_OFF    (CNT_OFF + 1024*CSTRIDE)   // ei:    [1000][512] float2 (ent,idx)
#define WN_OFF    (EI_OFF + CC*SLOT*2)       // wn:    [1000][512]
#define ZP_OFF    (WN_OFF + CC*DD)           // zpart: [32][256][512]
#define PP_OFF    (ZP_OFF + SK1*BB*DD)       // ppart: [8][256][1000]

// barrier words live in the unused tail of the cnt region (classes use <16000)
#define BAR_CNT_IDX  (1008*CSTRIDE)
#define BAR_FLAG_IDX (1012*CSTRIDE)

#define SMEM_F 3712        // 14848 B shared overlay (max phase = class_weights 3588)

// ---- MALL-coherent (write-through) stores for cross-phase intermediates ----
// sc0 sc1 => coherent at the device coherence point (Infinity Cache). No dirty
// L2 lines => barriers need NO buffer_wbl2 / buffer_inv at all.
typedef float f32x4 __attribute__((ext_vector_type(4)));
typedef float f32x2 __attribute__((ext_vector_type(2)));

__device__ __forceinline__ void st_wc4(float* p, float4 v) {
  f32x4 w = {v.x, v.y, v.z, v.w};
  asm volatile("global_store_dwordx4 %0, %1, off sc0 sc1" :: "v"(p), "v"(w) : "memory");
}
__device__ __forceinline__ void st_wc2(float* p, float a, float b) {
  f32x2 w = {a, b};
  asm volatile("global_store_dwordx2 %0, %1, off sc0 sc1" :: "v"(p), "v"(w) : "memory");
}
__device__ __forceinline__ void st_wc1(float* p, float a) {
  asm volatile("global_store_dword %0, %1, off sc0 sc1" :: "v"(p), "v"(a) : "memory");
}
// coherent 8B load (for ei: written in two phases, so L1/L2 must be bypassed)
__device__ __forceinline__ float2 ld_cv2(const float2* p) {
  unsigned long long r = __hip_atomic_load((const unsigned long long*)p,
      __ATOMIC_RELAXED, __HIP_MEMORY_SCOPE_AGENT);
  float2 o;
  o.x = __uint_as_float((unsigned)(r & 0xffffffffULL));
  o.y = __uint_as_float((unsigned)(r >> 32));
  return o;
}
__device__ __forceinline__ int ld_ci(const int* p) {
  return __hip_atomic_load(p, __ATOMIC_RELAXED, __HIP_MEMORY_SCOPE_AGENT);
}

// ---- device-wide sense barrier: NO cache maintenance (data is sc1-coherent).
// Every wave drains its own vmcnt (sc1 stores ack at the coherence point),
// then one thread per block joins a relaxed atomic counter + flag poll.
__device__ __forceinline__ void gsync(int* bcnt, int* bflag, int epoch) {
  asm volatile("s_waitcnt vmcnt(0) lgkmcnt(0)" ::: "memory");
  __syncthreads();
  if (threadIdx.x == 0) {
    int t = __hip_atomic_fetch_add(bcnt, 1, __ATOMIC_RELAXED,
                                   __HIP_MEMORY_SCOPE_AGENT);
    if (t == epoch * NBLK - 1) {
      __hip_atomic_store(bflag, epoch, __ATOMIC_RELAXED,
                         __HIP_MEMORY_SCOPE_AGENT);
    } else {
      while (__hip_atomic_load(bflag, __ATOMIC_RELAXED,
                               __HIP_MEMORY_SCOPE_AGENT) < epoch)
        __builtin_amdgcn_s_sleep(4);    // ~256-cycle poll period
    }
  }
  __syncthreads();
}

// ---- per-class select-K + normalized row-sum + column norm (verified body) ----
__device__ __forceinline__ void do_class(
    int c, int tid, float* smem, const float* supports_in, const float* z,
    const float2* ei, const int* cnt, float* wn) {
  int*   sel = (int*)smem;                       // [512]
  float* se  = smem + SLOT;                      // [512]
  int*   si  = (int*)(smem + 2*SLOT);            // [512]
  float (*part)[DD] = (float(*)[DD])(smem + 3*SLOT);  // [4][512]
  float* tot = smem + 3*SLOT + 4*DD;             // [4]
  const int lane = tid & 63, wid = tid >> 6;
  int n = ld_ci(&cnt[c * CSTRIDE]); if (n > SLOT) n = SLOT;

  int seln;
  if (n <= FILTER_K) {
    seln = n;
    for (int i = tid; i < n; i += 256)
      sel[i] = __float_as_int(ld_cv2(&ei[(size_t)c * SLOT + i]).y);
  } else {
    for (int i = tid; i < SLOT; i += 256) {
      if (i < n) {
        float2 pr = ld_cv2(&ei[(size_t)c * SLOT + i]);
        se[i] = pr.x; si[i] = __float_as_int(pr.y);
      } else { se[i] = INFINITY; si[i] = 0x7fffffff; }
    }
    __syncthreads();
    for (int k = 2; k <= SLOT; k <<= 1)
      for (int j = k >> 1; j > 0; j >>= 1) {
        for (int i = tid; i < SLOT; i += 256) {
          int ixj = i ^ j;
          if (ixj > i) {
            bool up = ((i & k) == 0);
            float e1 = se[i], e2 = se[ixj];
            int i1 = si[i], i2 = si[ixj];
            bool gt = (e1 > e2) || (e1 == e2 && i1 > i2);
            if (gt == up) { se[i] = e2; se[ixj] = e1; si[i] = i2; si[ixj] = i1; }
          }
        }
        __syncthreads();
      }
    seln = FILTER_K;
    for (int i = tid; i < FILTER_K; i += 256) sel[i] = si[i];
  }
  __syncthreads();
  const int seln_pad = (seln + 15) & ~15;
  if (seln > 0)
    for (int i = seln + tid; i < seln_pad; i += 256) sel[i] = sel[0];
  __syncthreads();

  // lane owns dims [lane*8, lane*8+8); wave handles 4 rows per iteration
  float4 a0 = make_float4(0.f, 0.f, 0.f, 0.f), a1 = a0;
  for (int t = wid * 4; t < seln_pad; t += 16) {
    float4 u0[4], u1[4]; float s[4];
#pragma unroll
    for (int j = 0; j < 4; ++j) {
      int r = sel[t + j];
      const float4* p4 = (const float4*)((r < NN)
          ? supports_in + (size_t)r * DD : z + (size_t)(r - NN) * DD);
      u0[j] = p4[lane * 2]; u1[j] = p4[lane * 2 + 1];
    }
#pragma unroll
    for (int j = 0; j < 4; ++j)
      s[j] = u0[j].x * u0[j].x + u0[j].y * u0[j].y + u0[j].z * u0[j].z
           + u0[j].w * u0[j].w + u1[j].x * u1[j].x + u1[j].y * u1[j].y
           + u1[j].z * u1[j].z + u1[j].w * u1[j].w;
#pragma unroll
    for (int o = 1; o < 64; o <<= 1) {
#pragma unroll
      for (int j = 0; j < 4; ++j) s[j] += __shfl_xor(s[j], o, 64);
    }
#pragma unroll
    for (int j = 0; j < 4; ++j) {
      float sc = (t + j < seln) ? 1.0f / fmaxf(sqrtf(s[j]), 1e-12f) : 0.f;
      a0.x += u0[j].x * sc; a0.y += u0[j].y * sc;
      a0.z += u0[j].z * sc; a0.w += u0[j].w * sc;
      a1.x += u1[j].x * sc; a1.y += u1[j].y * sc;
      a1.z += u1[j].z * sc; a1.w += u1[j].w * sc;
    }
  }

  *(float4*)&part[wid][lane * 8] = a0;
  *(float4*)&part[wid][lane * 8 + 4] = a1;
  __syncthreads();
  const int d = tid * 2;
  float wx = part[0][d] + part[1][d] + part[2][d] + part[3][d];
  float wy = part[0][d + 1] + part[1][d + 1] + part[2][d + 1] + part[3][d + 1];
  float ss = wx * wx + wy * wy;
#pragma unroll
  for (int o = 1; o < 64; o <<= 1) ss += __shfl_xor(ss, o, 64);
  if (lane == 0) tot[wid] = ss;
  __syncthreads();
  float S = tot[0] + tot[1] + tot[2] + tot[3];
  float sc = 1.0f / fmaxf(sqrtf(S), 1e-12f);
  st_wc2(wn + (size_t)c * DD + 2 * tid, wx * sc, wy * sc);
}

// =================== the persistent mega-kernel ===================
__global__ __launch_bounds__(256, 2) void mega(
    const float* x, const float* Wf, const float* Wc, const float* bc,
    const float* supports_in, const float* ent_in, const int* labels_idx,
    float* out, float* ws) {
  __shared__ __align__(16) float smem[SMEM_F];
  float*  z     = ws + Z_OFF;
  int*    cnt   = (int*)(ws + CNT_OFF);
  float2* ei    = (float2*)(ws + EI_OFF);
  float*  wn    = ws + WN_OFF;
  float*  zpart = ws + ZP_OFF;
  float*  ppart = ws + PP_OFF;
  int* bar_cnt  = cnt + BAR_CNT_IDX;
  int* bar_flag = cnt + BAR_FLAG_IDX;
  const int bid = blockIdx.x, tid = threadIdx.x;

  // ---- Phase 1: zpart = x@Wf split-K, ALL 512 blocks (SK1=32, klen=64) ----
  {
    float (*As)[68]  = (float(*)[68])smem;
    float (*Bs)[132] = (float(*)[132])(smem + 16 * 68);
    const int m0 = ((bid >> 2) & 3) * 64;
    const int n0 = (bid & 3) * 128;
    const int k0 = (bid >> 4) * 64;
    const int ar = tid >> 2, ac = (tid & 3) * 4;
    const int br = tid >> 4, bcn = (tid & 15) * 8;
    const int tm = (tid >> 4) * 4, tn = (tid & 15) * 4;
    float acc[4][8] = {};
    float4 av  = *(const float4*)&x[(size_t)(m0 + ar) * DIN + k0 + ac];
    float4 bv0 = *(const float4*)&Wf[(size_t)(k0 + br) * DD + n0 + bcn];
    float4 bv1 = *(const float4*)&Wf[(size_t)(k0 + br) * DD + n0 + bcn + 4];
    for (int kk = 0; kk < 64; kk += 16) {
      __syncthreads();
      As[ac + 0][ar] = av.x; As[ac + 1][ar] = av.y;
      As[ac + 2][ar] = av.z; As[ac + 3][ar] = av.w;
      *(float4*)&Bs[br][bcn] = bv0;
      *(float4*)&Bs[br][bcn + 4] = bv1;
      __syncthreads();
      if (kk + 16 < 64) {   // register prefetch of next K-tile
        av  = *(const float4*)&x[(size_t)(m0 + ar) * DIN + k0 + kk + 16 + ac];
        bv0 = *(const float4*)&Wf[(size_t)(k0 + kk + 16 + br) * DD + n0 + bcn];
        bv1 = *(const float4*)&Wf[(size_t)(k0 + kk + 16 + br) * DD + n0 + bcn + 4];
      }
#pragma unroll
      for (int q = 0; q < 16; ++q) {
        float4 a  = *(const float4*)&As[q][tm];
        float4 b0 = *(const float4*)&Bs[q][tn];
        float4 b1 = *(const float4*)&Bs[q][tn + 64];
        float aa[4] = {a.x, a.y, a.z, a.w};
        float bb[8] = {b0.x, b0.y, b0.z, b0.w, b1.x, b1.y, b1.z, b1.w};
#pragma unroll
        for (int i = 0; i < 4; ++i)
#pragma unroll
          for (int j = 0; j < 8; ++j) acc[i][j] += aa[i] * bb[j];
      }
    }
    float* Cb = zpart + (size_t)(bid >> 4) * BB * DD;
#pragma unroll
    for (int i = 0; i < 4; ++i) {
      st_wc4(&Cb[(size_t)(m0 + tm + i) * DD + n0 + tn],
             make_float4(acc[i][0], acc[i][1], acc[i][2], acc[i][3]));
      st_wc4(&Cb[(size_t)(m0 + tm + i) * DD + n0 + 64 + tn],
             make_float4(acc[i][4], acc[i][5], acc[i][6], acc[i][7]));
    }
  }
  gsync(bar_cnt, bar_flag, 1);

  // ---- Phase 2: z = sum of 32 partials (blocks 0..127) | old-row scatter
  // ---- (blocks 128..323); remaining blocks idle through the barrier. ----
  if (bid < 128) {
    const int n4 = BB * DD / 4;
    int i = bid * 256 + tid;
    if (i < n4) {
      const float4* p4 = (const float4*)zpart;
      float4 a = p4[i];
#pragma unroll
      for (int s = 1; s < SK1; ++s) {
        float4 b = p4[(size_t)s * n4 + i];
        a.x += b.x; a.y += b.y; a.z += b.z; a.w += b.w;
      }
      st_wc4(z + 4 * (size_t)i, a);
    }
  } else if (bid < 324) {
    int m = (bid - 128) * 256 + tid;
    if (m < NN) {
      int c = labels_idx[m];
      int pos = atomicAdd(&cnt[c * CSTRIDE], 1);
      if (pos < SLOT) {
        st_wc2((float*)&ei[(size_t)c * SLOT + pos], ent_in[m], __int_as_float(m));
      }
    }
  }
  gsync(bar_cnt, bar_flag, 2);

  // ---- Phase 3: ppart[s] = z @ Wc^T (all 512 blocks; 64x64 tile, klen 64) ----
  {
    float (*As)[68] = (float(*)[68])smem;
    float (*Bs)[68] = (float(*)[68])(smem + 16 * 68);
    const int n0 = (bid & 15) * 64;
    const int m0 = ((bid >> 4) & 3) * 64;
    const int ks = bid >> 6;            // 0..7
    const int k0 = ks * 64;
    const int ar = tid >> 2, ac = (tid & 3) * 4;
    const int tm = (tid >> 4) * 4, tn = (tid & 15) * 4;
    float acc[4][4] = {};
    float4 av = *(const float4*)&z[(size_t)(m0 + ar) * DD + k0 + ac];
    float4 bv = make_float4(0.f, 0.f, 0.f, 0.f);
    if (n0 + ar < CC) bv = *(const float4*)&Wc[(size_t)(n0 + ar) * DD + k0 + ac];
    for (int kk = 0; kk < 64; kk += 16) {
      __syncthreads();
      As[ac + 0][ar] = av.x; As[ac + 1][ar] = av.y;
      As[ac + 2][ar] = av.z; As[ac + 3][ar] = av.w;
      Bs[ac + 0][ar] = bv.x; Bs[ac + 1][ar] = bv.y;
      Bs[ac + 2][ar] = bv.z; Bs[ac + 3][ar] = bv.w;
      __syncthreads();
      if (kk + 16 < 64) {
        av = *(const float4*)&z[(size_t)(m0 + ar) * DD + k0 + kk + 16 + ac];
        if (n0 + ar < CC)
          bv = *(const float4*)&Wc[(size_t)(n0 + ar) * DD + k0 + kk + 16 + ac];
      }
#pragma unroll
      for (int q = 0; q < 16; ++q) {
        float4 a = *(const float4*)&As[q][tm];
        float4 b = *(const float4*)&Bs[q][tn];
        float aa[4] = {a.x, a.y, a.z, a.w};
        float bb[4] = {b.x, b.y, b.z, b.w};
#pragma unroll
        for (int i = 0; i < 4; ++i)
#pragma unroll
          for (int j = 0; j < 4; ++j) acc[i][j] += aa[i] * bb[j];
      }
    }
    float* Cb = ppart + (size_t)ks * BB * CC;
#pragma unroll
    for (int i = 0; i < 4; ++i) {
      int n = n0 + tn;
      if (n + 3 < CC) {
        st_wc4(&Cb[(size_t)(m0 + tm + i) * CC + n],
               make_float4(acc[i][0], acc[i][1], acc[i][2], acc[i][3]));
      } else {
#pragma unroll
        for (int j = 0; j < 4; ++j)
          if (n + j < CC) st_wc1(&Cb[(size_t)(m0 + tm + i) * CC + n + j], acc[i][j]);
      }
    }
  }
  gsync(bar_cnt, bar_flag, 3);

  // ---- Phase 4: rowstats — argmax+entropy over p partials; new-row scatter ----
  if (bid < BB) {
    float* smv = smem; int* smi = (int*)(smem + 4);
    float* ssm = smem + 8; float* tsm = smem + 12;
    const int b = bid;
    const int lane = tid & 63, wid = tid >> 6;
    float r[4];
    float mv = -INFINITY; int mi = 0x7fffffff;
#pragma unroll
    for (int i = 0; i < 4; ++i) {
      int c = tid + 256 * i;
      if (c < CC) {
        float v = bc[c];
#pragma unroll
        for (int s = 0; s < SKP; ++s)
          v += ppart[(size_t)s * BB * CC + (size_t)b * CC + c];
        r[i] = v;
      } else r[i] = -INFINITY;
      if (r[i] > mv) { mv = r[i]; mi = c; }
    }
#pragma unroll
    for (int o = 32; o > 0; o >>= 1) {
      float ov = __shfl_down(mv, o, 64);
      int oi = __shfl_down(mi, o, 64);
      if (ov > mv || (ov == mv && oi < mi)) { mv = ov; mi = oi; }
    }
    if (lane == 0) { smv[wid] = mv; smi[wid] = mi; }
    __syncthreads();
    if (tid == 0) {
#pragma unroll
      for (int w = 1; w < 4; ++w)
        if (smv[w] > smv[0] || (smv[w] == smv[0] && smi[w] < smi[0])) {
          smv[0] = smv[w]; smi[0] = smi[w];
        }
    }
    __syncthreads();
    const float m = smv[0]; const int am = smi[0];
    float s = 0.f, t = 0.f;
#pragma unroll
    for (int i = 0; i < 4; ++i) {
      if (tid + 256 * i < CC) {
        float u = r[i] - m;
        float e = expf(u);
        s += e; t += u * e;
      }
    }
#pragma unroll
    for (int o = 32; o > 0; o >>= 1) {
      s += __shfl_down(s, o, 64);
      t += __shfl_down(t, o, 64);
    }
    if (lane == 0) { ssm[wid] = s; tsm[wid] = t; }
    __syncthreads();
    if (tid == 0) {
      float S = ssm[0] + ssm[1] + ssm[2] + ssm[3];
      float T = tsm[0] + tsm[1] + tsm[2] + tsm[3];
      float ent = logf(S) - T / S;
      int pos = atomicAdd(&cnt[am * CSTRIDE], 1);
      if (pos < SLOT) {
        st_wc2((float*)&ei[(size_t)am * SLOT + pos], ent, __int_as_float(NN + b));
      }
    }
  }
  gsync(bar_cnt, bar_flag, 4);

  // ---- Phase 5: class weights (each block: class bid, then bid+512) ----
  do_class(bid, tid, smem, supports_in, z, ei, cnt, wn);
  __syncthreads();
  if (bid + 512 < CC)
    do_class(bid + 512, tid, smem, supports_in, z, ei, cnt, wn);
  gsync(bar_cnt, bar_flag, 5);

  // ---- Phase 6: out = z @ wn^T (blocks 0..255; 16x64 tile, full K=512) ----
  if (bid < 256) {
    float (*As)[20] = (float(*)[20])smem;           // [k][row]
    float (*Bs)[68] = (float(*)[68])(smem + 16 * 20);
    const int m0 = (bid >> 4) * 16;
    const int n0 = (bid & 15) * 64;
    const int arow = tid >> 4, ak = tid & 15;
    const int br = tid >> 2, bcl = (tid & 3) * 4;
    const int tr = tid >> 4, tn4 = (tid & 15) * 4;
    float acc[4] = {};
    float av = z[(size_t)(m0 + arow) * DD + ak];
    float4 bv = make_float4(0.f, 0.f, 0.f, 0.f);
    if (n0 + br < CC) bv = *(const float4*)&wn[(size_t)(n0 + br) * DD + bcl];
    for (int k0 = 0; k0 < DD; k0 += 16) {
      __syncthreads();
      As[ak][arow] = av;
      Bs[bcl + 0][br] = bv.x; Bs[bcl + 1][br] = bv.y;
      Bs[bcl + 2][br] = bv.z; Bs[bcl + 3][br] = bv.w;
      __syncthreads();
      if (k0 + 16 < DD) {
        av = z[(size_t)(m0 + arow) * DD + k0 + 16 + ak];
        if (n0 + br < CC)
          bv = *(const float4*)&wn[(size_t)(n0 + br) * DD + k0 + 16 + bcl];
      }
#pragma unroll
      for (int q = 0; q < 16; ++q) {
        float a = As[q][tr];
        float4 b = *(const float4*)&Bs[q][tn4];
        acc[0] += a * b.x; acc[1] += a * b.y;
        acc[2] += a * b.z; acc[3] += a * b.w;
      }
    }
    int n = n0 + tn4;
    if (n + 3 < CC) {
      *(float4*)&out[(size_t)(m0 + tr) * CC + n] =
          make_float4(acc[0], acc[1], acc[2], acc[3]);
    } else {
#pragma unroll
      for (int j = 0; j < 4; ++j)
        if (n + j < CC) out[(size_t)(m0 + tr) * CC + n + j] = acc[j];
    }
  }
}

// ============================ launcher ===================================
extern "C" void kernel_launch(void* const* d_in, const int* in_sizes, int n_in,
                              void* d_out, int out_size, void* d_ws, size_t ws_size,
                              hipStream_t stream) {
  (void)in_sizes; (void)n_in; (void)out_size; (void)ws_size;
  const float* x           = (const float*)d_in[0];
  const float* Wf          = (const float*)d_in[1];
  const float* Wc          = (const float*)d_in[2];
  const float* bc          = (const float*)d_in[3];
  const float* supports_in = (const float*)d_in[4];
  const float* ent_in      = (const float*)d_in[5];
  const int*   labels_idx  = (const int*)d_in[6];
  float* out = (float*)d_out;
  float* W = (float*)d_ws;
  int* cnt = (int*)(W + CNT_OFF);

  // zero class counters + barrier words (64 KB, covers idx 0..16383)
  hipMemsetAsync(cnt, 0, 1024 * CSTRIDE * sizeof(int), stream);
  // single persistent kernel; 512 blocks = 2/CU guaranteed resident
  hipLaunchKernelGGL(mega, dim3(NBLK), dim3(256), 0, stream,
                     x, Wf, Wc, bc, supports_in, ent_in, labels_idx, out, W);
}

// Round 4
// 218.873 us; speedup vs baseline: 1.9458x; 1.0448x over previous
//
#include <hip/hip_runtime.h>
#include <math.h>

// Problem constants (fixed by setup_inputs)
#define BB   256
#define DIN  2048
#define DD   512
#define CC   1000
#define NN   50000
#define FILTER_K 100
#define SLOT 512           // per-class capacity; max real ~90 old + <=256 new
#define CSTRIDE 16         // one counter per 64B cacheline (atomic contention)

#define SK1  32            // split-K for z = x@Wf  (klen 64)
#define SKP  8             // split-K for p = z@Wc^T (klen 64)
#define NBLK 512           // persistent grid: 2 blocks/CU, guaranteed resident
#define NGRP 8             // barrier arrival groups (two-level barrier)
#define GSZ  (NBLK / NGRP) // 64 blocks per group

// ---------------- workspace layout (float elements) ----------------
#define Z_OFF     0                          // z:     [256][512]
#define CNT_OFF   (Z_OFF + BB*DD)            // cnt:   [1024*16] int (strided)
#define EI_OFF    (CNT_OFF + 1024*CSTRIDE)   // ei:    [1000][512] float2 (ent,idx)
#define WN_OFF    (EI_OFF + CC*SLOT*2)       // wn:    [1000][512]
#define ZP_OFF    (WN_OFF + CC*DD)           // zpart: [32][256][512]
#define PP_OFF    (ZP_OFF + SK1*BB*DD)       // ppart: [8][256][1000]

// barrier words live in the unused tail of the cnt region (classes use idx < 16000)
// group counters on separate cachelines (128B apart) to parallelize MALL RMWs
#define BAR_GRP(g)  ((1000 + 2*(g)) * CSTRIDE)   // ints 16000..16224
#define BAR_GLB     (1016 * CSTRIDE)             // int  16256
#define BAR_FLG     (1020 * CSTRIDE)             // int  16320  (< 16384, memset'd)

#define SMEM_F 3712        // 14848 B shared overlay (max phase = class_weights 3588)

// ---- MALL-coherent (write-through) stores for cross-phase intermediates ----
// sc0 sc1 => coherent at the device coherence point (Infinity Cache). No dirty
// L2 lines => barriers need NO buffer_wbl2 / buffer_inv at all.
typedef float f32x4 __attribute__((ext_vector_type(4)));
typedef float f32x2 __attribute__((ext_vector_type(2)));

__device__ __forceinline__ void st_wc4(float* p, float4 v) {
  f32x4 w = {v.x, v.y, v.z, v.w};
  asm volatile("global_store_dwordx4 %0, %1, off sc0 sc1" :: "v"(p), "v"(w) : "memory");
}
__device__ __forceinline__ void st_wc2(float* p, float a, float b) {
  f32x2 w = {a, b};
  asm volatile("global_store_dwordx2 %0, %1, off sc0 sc1" :: "v"(p), "v"(w) : "memory");
}
__device__ __forceinline__ void st_wc1(float* p, float a) {
  asm volatile("global_store_dword %0, %1, off sc0 sc1" :: "v"(p), "v"(a) : "memory");
}
// coherent 8B load (for ei: written in two phases, so L1/L2 must be bypassed)
__device__ __forceinline__ float2 ld_cv2(const float2* p) {
  unsigned long long r = __hip_atomic_load((const unsigned long long*)p,
      __ATOMIC_RELAXED, __HIP_MEMORY_SCOPE_AGENT);
  float2 o;
  o.x = __uint_as_float((unsigned)(r & 0xffffffffULL));
  o.y = __uint_as_float((unsigned)(r >> 32));
  return o;
}
__device__ __forceinline__ int ld_ci(const int* p) {
  return __hip_atomic_load(p, __ATOMIC_RELAXED, __HIP_MEMORY_SCOPE_AGENT);
}

// ---- device-wide sense barrier, two-level arrival, NO cache maintenance ----
// Level 1: 64 blocks/group RMW their own cacheline (8 lines concurrent at MALL).
// Level 2: 8 group-finalizers RMW one global line; last sets the flag.
// Data coherence comes from sc1 write-through + per-wave vmcnt drain.
__device__ __forceinline__ void gsync(int* cnt, int epoch, int grp) {
  asm volatile("s_waitcnt vmcnt(0) lgkmcnt(0)" ::: "memory");
  __syncthreads();
  if (threadIdx.x == 0) {
    int t = __hip_atomic_fetch_add(&cnt[BAR_GRP(grp)], 1, __ATOMIC_RELAXED,
                                   __HIP_MEMORY_SCOPE_AGENT);
    bool set_flag = false;
    if (t == epoch * GSZ - 1) {          // last arriver of this group
      int u = __hip_atomic_fetch_add(&cnt[BAR_GLB], 1, __ATOMIC_RELAXED,
                                     __HIP_MEMORY_SCOPE_AGENT);
      if (u == epoch * NGRP - 1) {       // last group
        __hip_atomic_store(&cnt[BAR_FLG], epoch, __ATOMIC_RELAXED,
                           __HIP_MEMORY_SCOPE_AGENT);
        set_flag = true;
      }
    }
    if (!set_flag) {
      while (__hip_atomic_load(&cnt[BAR_FLG], __ATOMIC_RELAXED,
                               __HIP_MEMORY_SCOPE_AGENT) < epoch)
        __builtin_amdgcn_s_sleep(2);     // ~128-cycle poll period
    }
  }
  __syncthreads();
}

// ---- per-class select-K + normalized row-sum + column norm (verified body) ----
__device__ __forceinline__ void do_class(
    int c, int tid, float* smem, const float* supports_in, const float* z,
    const float2* ei, const int* cnt, float* wn) {
  int*   sel = (int*)smem;                       // [512]
  float* se  = smem + SLOT;                      // [512]
  int*   si  = (int*)(smem + 2*SLOT);            // [512]
  float (*part)[DD] = (float(*)[DD])(smem + 3*SLOT);  // [4][512]
  float* tot = smem + 3*SLOT + 4*DD;             // [4]
  const int lane = tid & 63, wid = tid >> 6;
  int n = ld_ci(&cnt[c * CSTRIDE]); if (n > SLOT) n = SLOT;

  int seln;
  if (n <= FILTER_K) {
    seln = n;
    for (int i = tid; i < n; i += 256)
      sel[i] = __float_as_int(ld_cv2(&ei[(size_t)c * SLOT + i]).y);
  } else {
    for (int i = tid; i < SLOT; i += 256) {
      if (i < n) {
        float2 pr = ld_cv2(&ei[(size_t)c * SLOT + i]);
        se[i] = pr.x; si[i] = __float_as_int(pr.y);
      } else { se[i] = INFINITY; si[i] = 0x7fffffff; }
    }
    __syncthreads();
    for (int k = 2; k <= SLOT; k <<= 1)
      for (int j = k >> 1; j > 0; j >>= 1) {
        for (int i = tid; i < SLOT; i += 256) {
          int ixj = i ^ j;
          if (ixj > i) {
            bool up = ((i & k) == 0);
            float e1 = se[i], e2 = se[ixj];
            int i1 = si[i], i2 = si[ixj];
            bool gt = (e1 > e2) || (e1 == e2 && i1 > i2);
            if (gt == up) { se[i] = e2; se[ixj] = e1; si[i] = i2; si[ixj] = i1; }
          }
        }
        __syncthreads();
      }
    seln = FILTER_K;
    for (int i = tid; i < FILTER_K; i += 256) sel[i] = si[i];
  }
  __syncthreads();
  const int seln_pad = (seln + 15) & ~15;
  if (seln > 0)
    for (int i = seln + tid; i < seln_pad; i += 256) sel[i] = sel[0];
  __syncthreads();

  // lane owns dims [lane*8, lane*8+8); wave handles 4 rows per iteration
  float4 a0 = make_float4(0.f, 0.f, 0.f, 0.f), a1 = a0;
  for (int t = wid * 4; t < seln_pad; t += 16) {
    float4 u0[4], u1[4]; float s[4];
#pragma unroll
    for (int j = 0; j < 4; ++j) {
      int r = sel[t + j];
      const float4* p4 = (const float4*)((r < NN)
          ? supports_in + (size_t)r * DD : z + (size_t)(r - NN) * DD);
      u0[j] = p4[lane * 2]; u1[j] = p4[lane * 2 + 1];
    }
#pragma unroll
    for (int j = 0; j < 4; ++j)
      s[j] = u0[j].x * u0[j].x + u0[j].y * u0[j].y + u0[j].z * u0[j].z
           + u0[j].w * u0[j].w + u1[j].x * u1[j].x + u1[j].y * u1[j].y
           + u1[j].z * u1[j].z + u1[j].w * u1[j].w;
#pragma unroll
    for (int o = 1; o < 64; o <<= 1) {
#pragma unroll
      for (int j = 0; j < 4; ++j) s[j] += __shfl_xor(s[j], o, 64);
    }
#pragma unroll
    for (int j = 0; j < 4; ++j) {
      float sc = (t + j < seln) ? 1.0f / fmaxf(sqrtf(s[j]), 1e-12f) : 0.f;
      a0.x += u0[j].x * sc; a0.y += u0[j].y * sc;
      a0.z += u0[j].z * sc; a0.w += u0[j].w * sc;
      a1.x += u1[j].x * sc; a1.y += u1[j].y * sc;
      a1.z += u1[j].z * sc; a1.w += u1[j].w * sc;
    }
  }

  *(float4*)&part[wid][lane * 8] = a0;
  *(float4*)&part[wid][lane * 8 + 4] = a1;
  __syncthreads();
  const int d = tid * 2;
  float wx = part[0][d] + part[1][d] + part[2][d] + part[3][d];
  float wy = part[0][d + 1] + part[1][d + 1] + part[2][d + 1] + part[3][d + 1];
  float ss = wx * wx + wy * wy;
#pragma unroll
  for (int o = 1; o < 64; o <<= 1) ss += __shfl_xor(ss, o, 64);
  if (lane == 0) tot[wid] = ss;
  __syncthreads();
  float S = tot[0] + tot[1] + tot[2] + tot[3];
  float sc = 1.0f / fmaxf(sqrtf(S), 1e-12f);
  st_wc2(wn + (size_t)c * DD + 2 * tid, wx * sc, wy * sc);
}

// =================== the persistent mega-kernel ===================
__global__ __launch_bounds__(256, 2) void mega(
    const float* x, const float* Wf, const float* Wc, const float* bc,
    const float* supports_in, const float* ent_in, const int* labels_idx,
    float* out, float* ws) {
  __shared__ __align__(16) float smem[SMEM_F];
  float*  z     = ws + Z_OFF;
  int*    cnt   = (int*)(ws + CNT_OFF);
  float2* ei    = (float2*)(ws + EI_OFF);
  float*  wn    = ws + WN_OFF;
  float*  zpart = ws + ZP_OFF;
  float*  ppart = ws + PP_OFF;
  const int bid = blockIdx.x, tid = threadIdx.x;
  const int grp = bid >> 6;            // 8 groups of 64 blocks

  // ---- Phase 1: zpart = x@Wf split-K, ALL 512 blocks (SK1=32, klen=64) ----
  {
    float (*As)[68]  = (float(*)[68])smem;
    float (*Bs)[132] = (float(*)[132])(smem + 16 * 68);
    const int m0 = ((bid >> 2) & 3) * 64;
    const int n0 = (bid & 3) * 128;
    const int k0 = (bid >> 4) * 64;
    const int ar = tid >> 2, ac = (tid & 3) * 4;
    const int br = tid >> 4, bcn = (tid & 15) * 8;
    const int tm = (tid >> 4) * 4, tn = (tid & 15) * 4;
    float acc[4][8] = {};
    float4 av  = *(const float4*)&x[(size_t)(m0 + ar) * DIN + k0 + ac];
    float4 bv0 = *(const float4*)&Wf[(size_t)(k0 + br) * DD + n0 + bcn];
    float4 bv1 = *(const float4*)&Wf[(size_t)(k0 + br) * DD + n0 + bcn + 4];
    for (int kk = 0; kk < 64; kk += 16) {
      __syncthreads();
      As[ac + 0][ar] = av.x; As[ac + 1][ar] = av.y;
      As[ac + 2][ar] = av.z; As[ac + 3][ar] = av.w;
      *(float4*)&Bs[br][bcn] = bv0;
      *(float4*)&Bs[br][bcn + 4] = bv1;
      __syncthreads();
      if (kk + 16 < 64) {   // register prefetch of next K-tile
        av  = *(const float4*)&x[(size_t)(m0 + ar) * DIN + k0 + kk + 16 + ac];
        bv0 = *(const float4*)&Wf[(size_t)(k0 + kk + 16 + br) * DD + n0 + bcn];
        bv1 = *(const float4*)&Wf[(size_t)(k0 + kk + 16 + br) * DD + n0 + bcn + 4];
      }
#pragma unroll
      for (int q = 0; q < 16; ++q) {
        float4 a  = *(const float4*)&As[q][tm];
        float4 b0 = *(const float4*)&Bs[q][tn];
        float4 b1 = *(const float4*)&Bs[q][tn + 64];
        float aa[4] = {a.x, a.y, a.z, a.w};
        float bb[8] = {b0.x, b0.y, b0.z, b0.w, b1.x, b1.y, b1.z, b1.w};
#pragma unroll
        for (int i = 0; i < 4; ++i)
#pragma unroll
          for (int j = 0; j < 8; ++j) acc[i][j] += aa[i] * bb[j];
      }
    }
    float* Cb = zpart + (size_t)(bid >> 4) * BB * DD;
#pragma unroll
    for (int i = 0; i < 4; ++i) {
      st_wc4(&Cb[(size_t)(m0 + tm + i) * DD + n0 + tn],
             make_float4(acc[i][0], acc[i][1], acc[i][2], acc[i][3]));
      st_wc4(&Cb[(size_t)(m0 + tm + i) * DD + n0 + 64 + tn],
             make_float4(acc[i][4], acc[i][5], acc[i][6], acc[i][7]));
    }
  }
  gsync(cnt, 1, grp);

  // ---- Phase 2: z = sum of 32 partials (blocks 0..127) | old-row scatter
  // ---- (blocks 128..323); remaining blocks idle through the barrier. ----
  if (bid < 128) {
    const int n4 = BB * DD / 4;
    int i = bid * 256 + tid;
    if (i < n4) {
      const float4* p4 = (const float4*)zpart;
      float4 a = p4[i];
#pragma unroll
      for (int s = 1; s < SK1; ++s) {
        float4 b = p4[(size_t)s * n4 + i];
        a.x += b.x; a.y += b.y; a.z += b.z; a.w += b.w;
      }
      st_wc4(z + 4 * (size_t)i, a);
    }
  } else if (bid < 324) {
    int m = (bid - 128) * 256 + tid;
    if (m < NN) {
      int c = labels_idx[m];
      int pos = atomicAdd(&cnt[c * CSTRIDE], 1);
      if (pos < SLOT) {
        st_wc2((float*)&ei[(size_t)c * SLOT + pos], ent_in[m], __int_as_float(m));
      }
    }
  }
  gsync(cnt, 2, grp);

  // ---- Phase 3: ppart[s] = z @ Wc^T (all 512 blocks; 64x64 tile, klen 64) ----
  {
    float (*As)[68] = (float(*)[68])smem;
    float (*Bs)[68] = (float(*)[68])(smem + 16 * 68);
    const int n0 = (bid & 15) * 64;
    const int m0 = ((bid >> 4) & 3) * 64;
    const int ks = bid >> 6;            // 0..7
    const int k0 = ks * 64;
    const int ar = tid >> 2, ac = (tid & 3) * 4;
    const int tm = (tid >> 4) * 4, tn = (tid & 15) * 4;
    float acc[4][4] = {};
    float4 av = *(const float4*)&z[(size_t)(m0 + ar) * DD + k0 + ac];
    float4 bv = make_float4(0.f, 0.f, 0.f, 0.f);
    if (n0 + ar < CC) bv = *(const float4*)&Wc[(size_t)(n0 + ar) * DD + k0 + ac];
    for (int kk = 0; kk < 64; kk += 16) {
      __syncthreads();
      As[ac + 0][ar] = av.x; As[ac + 1][ar] = av.y;
      As[ac + 2][ar] = av.z; As[ac + 3][ar] = av.w;
      Bs[ac + 0][ar] = bv.x; Bs[ac + 1][ar] = bv.y;
      Bs[ac + 2][ar] = bv.z; Bs[ac + 3][ar] = bv.w;
      __syncthreads();
      if (kk + 16 < 64) {
        av = *(const float4*)&z[(size_t)(m0 + ar) * DD + k0 + kk + 16 + ac];
        if (n0 + ar < CC)
          bv = *(const float4*)&Wc[(size_t)(n0 + ar) * DD + k0 + kk + 16 + ac];
      }
#pragma unroll
      for (int q = 0; q < 16; ++q) {
        float4 a = *(const float4*)&As[q][tm];
        float4 b = *(const float4*)&Bs[q][tn];
        float aa[4] = {a.x, a.y, a.z, a.w};
        float bb[4] = {b.x, b.y, b.z, b.w};
#pragma unroll
        for (int i = 0; i < 4; ++i)
#pragma unroll
          for (int j = 0; j < 4; ++j) acc[i][j] += aa[i] * bb[j];
      }
    }
    float* Cb = ppart + (size_t)ks * BB * CC;
#pragma unroll
    for (int i = 0; i < 4; ++i) {
      int n = n0 + tn;
      if (n + 3 < CC) {
        st_wc4(&Cb[(size_t)(m0 + tm + i) * CC + n],
               make_float4(acc[i][0], acc[i][1], acc[i][2], acc[i][3]));
      } else {
#pragma unroll
        for (int j = 0; j < 4; ++j)
          if (n + j < CC) st_wc1(&Cb[(size_t)(m0 + tm + i) * CC + n + j], acc[i][j]);
      }
    }
  }
  gsync(cnt, 3, grp);

  // ---- Phase 4: rowstats — argmax+entropy over p partials; new-row scatter ----
  if (bid < BB) {
    float* smv = smem; int* smi = (int*)(smem + 4);
    float* ssm = smem + 8; float* tsm = smem + 12;
    const int b = bid;
    const int lane = tid & 63, wid = tid >> 6;
    float r[4];
    float mv = -INFINITY; int mi = 0x7fffffff;
#pragma unroll
    for (int i = 0; i < 4; ++i) {
      int c = tid + 256 * i;
      if (c < CC) {
        float v = bc[c];
#pragma unroll
        for (int s = 0; s < SKP; ++s)
          v += ppart[(size_t)s * BB * CC + (size_t)b * CC + c];
        r[i] = v;
      } else r[i] = -INFINITY;
      if (r[i] > mv) { mv = r[i]; mi = c; }
    }
#pragma unroll
    for (int o = 32; o > 0; o >>= 1) {
      float ov = __shfl_down(mv, o, 64);
      int oi = __shfl_down(mi, o, 64);
      if (ov > mv || (ov == mv && oi < mi)) { mv = ov; mi = oi; }
    }
    if (lane == 0) { smv[wid] = mv; smi[wid] = mi; }
    __syncthreads();
    if (tid == 0) {
#pragma unroll
      for (int w = 1; w < 4; ++w)
        if (smv[w] > smv[0] || (smv[w] == smv[0] && smi[w] < smi[0])) {
          smv[0] = smv[w]; smi[0] = smi[w];
        }
    }
    __syncthreads();
    const float m = smv[0]; const int am = smi[0];
    float s = 0.f, t = 0.f;
#pragma unroll
    for (int i = 0; i < 4; ++i) {
      if (tid + 256 * i < CC) {
        float u = r[i] - m;
        float e = expf(u);
        s += e; t += u * e;
      }
    }
#pragma unroll
    for (int o = 32; o > 0; o >>= 1) {
      s += __shfl_down(s, o, 64);
      t += __shfl_down(t, o, 64);
    }
    if (lane == 0) { ssm[wid] = s; tsm[wid] = t; }
    __syncthreads();
    if (tid == 0) {
      float S = ssm[0] + ssm[1] + ssm[2] + ssm[3];
      float T = tsm[0] + tsm[1] + tsm[2] + tsm[3];
      float ent = logf(S) - T / S;
      int pos = atomicAdd(&cnt[am * CSTRIDE], 1);
      if (pos < SLOT) {
        st_wc2((float*)&ei[(size_t)am * SLOT + pos], ent, __int_as_float(NN + b));
      }
    }
  }
  gsync(cnt, 4, grp);

  // ---- Phase 5: class weights (each block: class bid, then bid+512) ----
  do_class(bid, tid, smem, supports_in, z, ei, cnt, wn);
  __syncthreads();
  if (bid + 512 < CC)
    do_class(bid + 512, tid, smem, supports_in, z, ei, cnt, wn);
  gsync(cnt, 5, grp);

  // ---- Phase 6: out = z @ wn^T (blocks 0..255; 16x64 tile, full K=512) ----
  if (bid < 256) {
    float (*As)[20] = (float(*)[20])smem;           // [k][row]
    float (*Bs)[68] = (float(*)[68])(smem + 16 * 20);
    const int m0 = (bid >> 4) * 16;
    const int n0 = (bid & 15) * 64;
    const int arow = tid >> 4, ak = tid & 15;
    const int br = tid >> 2, bcl = (tid & 3) * 4;
    const int tr = tid >> 4, tn4 = (tid & 15) * 4;
    float acc[4] = {};
    float av = z[(size_t)(m0 + arow) * DD + ak];
    float4 bv = make_float4(0.f, 0.f, 0.f, 0.f);
    if (n0 + br < CC) bv = *(const float4*)&wn[(size_t)(n0 + br) * DD + bcl];
    for (int k0 = 0; k0 < DD; k0 += 16) {
      __syncthreads();
      As[ak][arow] = av;
      Bs[bcl + 0][br] = bv.x; Bs[bcl + 1][br] = bv.y;
      Bs[bcl + 2][br] = bv.z; Bs[bcl + 3][br] = bv.w;
      __syncthreads();
      if (k0 + 16 < DD) {
        av = z[(size_t)(m0 + arow) * DD + k0 + 16 + ak];
        if (n0 + br < CC)
          bv = *(const float4*)&wn[(size_t)(n0 + br) * DD + k0 + 16 + bcl];
      }
#pragma unroll
      for (int q = 0; q < 16; ++q) {
        float a = As[q][tr];
        float4 b = *(const float4*)&Bs[q][tn4];
        acc[0] += a * b.x; acc[1] += a * b.y;
        acc[2] += a * b.z; acc[3] += a * b.w;
      }
    }
    int n = n0 + tn4;
    if (n + 3 < CC) {
      *(float4*)&out[(size_t)(m0 + tr) * CC + n] =
          make_float4(acc[0], acc[1], acc[2], acc[3]);
    } else {
#pragma unroll
      for (int j = 0; j < 4; ++j)
        if (n + j < CC) out[(size_t)(m0 + tr) * CC + n + j] = acc[j];
    }
  }
}

// ============================ launcher ===================================
extern "C" void kernel_launch(void* const* d_in, const int* in_sizes, int n_in,
                              void* d_out, int out_size, void* d_ws, size_t ws_size,
                              hipStream_t stream) {
  (void)in_sizes; (void)n_in; (void)out_size; (void)ws_size;
  const float* x           = (const float*)d_in[0];
  const float* Wf          = (const float*)d_in[1];
  const float* Wc          = (const float*)d_in[2];
  const float* bc          = (const float*)d_in[3];
  const float* supports_in = (const float*)d_in[4];
  const float* ent_in      = (const float*)d_in[5];
  const int*   labels_idx  = (const int*)d_in[6];
  float* out = (float*)d_out;
  float* W = (float*)d_ws;
  int* cnt = (int*)(W + CNT_OFF);

  // zero class counters + barrier words (64 KB, covers idx 0..16383)
  hipMemsetAsync(cnt, 0, 1024 * CSTRIDE * sizeof(int), stream);
  // single persistent kernel; 512 blocks = 2/CU guaranteed resident
  hipLaunchKernelGGL(mega, dim3(NBLK), dim3(256), 0, stream,
                     x, Wf, Wc, bc, supports_in, ent_in, labels_idx, out, W);
}

// Round 6
// 218.673 us; speedup vs baseline: 1.9475x; 1.0009x over previous
//
#include <hip/hip_runtime.h>
#include <math.h>

// Problem constants (fixed by setup_inputs)
#define BB   256
#define DIN  2048
#define DD   512
#define CC   1000
#define NN   50000
#define FILTER_K 100
#define SLOT 512           // per-class capacity; max real ~90 old + <=256 new
#define CSTRIDE 16         // one counter per 64B cacheline (atomic contention)

#define SK1  32            // split-K for z = x@Wf  (klen 64)
#define SKP  8             // split-K for p = z@Wc^T (klen 64)
#define SKO  8             // split-K for out = z@wn^T (klen 64)
#define NBLK 512           // persistent grid: 2 blocks/CU, guaranteed resident
#define NGRP 8             // barrier arrival groups (two-level barrier)
#define GSZ  (NBLK / NGRP) // 64 blocks per group

// ---------------- workspace layout (float elements) ----------------
// one-writer-per-region discipline: every region is written by exactly ONE
// phase (sc0/sc1 write-through), then read. Never reuse a region for a second
// writer phase — stale clean L2 lines from earlier readers would survive.
#define Z_OFF     0                          // z:     [256][512]
#define CNT_OFF   (Z_OFF + BB*DD)            // cnt:   [1024*16] int (strided)
#define EI_OFF    (CNT_OFF + 1024*CSTRIDE)   // ei:    [1000][512] float2 (ent,idx)
#define WN_OFF    (EI_OFF + CC*SLOT*2)       // wn:    [1000][512]
#define ZP_OFF    (WN_OFF + CC*DD)           // zpart: [32][256][512]
#define PP_OFF    (ZP_OFF + SK1*BB*DD)       // ppart: [8][256][1000]
#define OP_OFF    (PP_OFF + SKP*BB*CC)       // opart: [8][256][1000] (fresh region)

// barrier words live in the unused tail of the cnt region (classes use idx < 16000)
// group counters on separate cachelines (128B apart) to parallelize MALL RMWs
#define BAR_GRP(g)  ((1000 + 2*(g)) * CSTRIDE)   // ints 16000..16224
#define BAR_GLB     (1016 * CSTRIDE)             // int  16256
#define BAR_FLG     (1020 * CSTRIDE)             // int  16320  (< 16384, memset'd)

#define SMEM_F 3712        // 14848 B shared overlay (max phase = class_weights 3588)

// ---- MALL-coherent (write-through) stores for cross-phase intermediates ----
// sc0 sc1 => coherent at the device coherence point (Infinity Cache). No dirty
// L2 lines => barriers need NO buffer_wbl2 / buffer_inv at all.
typedef float f32x4 __attribute__((ext_vector_type(4)));
typedef float f32x2 __attribute__((ext_vector_type(2)));

__device__ __forceinline__ void st_wc4(float* p, float4 v) {
  f32x4 w = {v.x, v.y, v.z, v.w};
  asm volatile("global_store_dwordx4 %0, %1, off sc0 sc1" :: "v"(p), "v"(w) : "memory");
}
__device__ __forceinline__ void st_wc2(float* p, float a, float b) {
  f32x2 w = {a, b};
  asm volatile("global_store_dwordx2 %0, %1, off sc0 sc1" :: "v"(p), "v"(w) : "memory");
}
__device__ __forceinline__ void st_wc1(float* p, float a) {
  asm volatile("global_store_dword %0, %1, off sc0 sc1" :: "v"(p), "v"(a) : "memory");
}
// coherent 8B load (for ei: written in two phases, so L1/L2 must be bypassed)
__device__ __forceinline__ float2 ld_cv2(const float2* p) {
  unsigned long long r = __hip_atomic_load((const unsigned long long*)p,
      __ATOMIC_RELAXED, __HIP_MEMORY_SCOPE_AGENT);
  float2 o;
  o.x = __uint_as_float((unsigned)(r & 0xffffffffULL));
  o.y = __uint_as_float((unsigned)(r >> 32));
  return o;
}
__device__ __forceinline__ int ld_ci(const int* p) {
  return __hip_atomic_load(p, __ATOMIC_RELAXED, __HIP_MEMORY_SCOPE_AGENT);
}

// ---- device-wide sense barrier, two-level arrival, NO cache maintenance ----
__device__ __forceinline__ void gsync(int* cnt, int epoch, int grp) {
  asm volatile("s_waitcnt vmcnt(0) lgkmcnt(0)" ::: "memory");
  __syncthreads();
  if (threadIdx.x == 0) {
    int t = __hip_atomic_fetch_add(&cnt[BAR_GRP(grp)], 1, __ATOMIC_RELAXED,
                                   __HIP_MEMORY_SCOPE_AGENT);
    bool set_flag = false;
    if (t == epoch * GSZ - 1) {          // last arriver of this group
      int u = __hip_atomic_fetch_add(&cnt[BAR_GLB], 1, __ATOMIC_RELAXED,
                                     __HIP_MEMORY_SCOPE_AGENT);
      if (u == epoch * NGRP - 1) {       // last group
        __hip_atomic_store(&cnt[BAR_FLG], epoch, __ATOMIC_RELAXED,
                           __HIP_MEMORY_SCOPE_AGENT);
        set_flag = true;
      }
    }
    if (!set_flag) {
      while (__hip_atomic_load(&cnt[BAR_FLG], __ATOMIC_RELAXED,
                               __HIP_MEMORY_SCOPE_AGENT) < epoch)
        __builtin_amdgcn_s_sleep(2);     // ~128-cycle poll period
    }
  }
  __syncthreads();
}

// ---- per-class select-K + normalized row-sum + column norm (ILP-8) ----
__device__ __forceinline__ void do_class(
    int c, int tid, float* smem, const float* supports_in, const float* z,
    const float2* ei, const int* cnt, float* wn) {
  int*   sel = (int*)smem;                       // [512]
  float* se  = smem + SLOT;                      // [512]
  int*   si  = (int*)(smem + 2*SLOT);            // [512]
  float (*part)[DD] = (float(*)[DD])(smem + 3*SLOT);  // [4][512]
  float* tot = smem + 3*SLOT + 4*DD;             // [4]
  const int lane = tid & 63, wid = tid >> 6;
  int n = ld_ci(&cnt[c * CSTRIDE]); if (n > SLOT) n = SLOT;

  int seln;
  if (n <= FILTER_K) {
    seln = n;
    for (int i = tid; i < n; i += 256)
      sel[i] = __float_as_int(ld_cv2(&ei[(size_t)c * SLOT + i]).y);
  } else {
    for (int i = tid; i < SLOT; i += 256) {
      if (i < n) {
        float2 pr = ld_cv2(&ei[(size_t)c * SLOT + i]);
        se[i] = pr.x; si[i] = __float_as_int(pr.y);
      } else { se[i] = INFINITY; si[i] = 0x7fffffff; }
    }
    __syncthreads();
    for (int k = 2; k <= SLOT; k <<= 1)
      for (int j = k >> 1; j > 0; j >>= 1) {
        for (int i = tid; i < SLOT; i += 256) {
          int ixj = i ^ j;
          if (ixj > i) {
            bool up = ((i & k) == 0);
            float e1 = se[i], e2 = se[ixj];
            int i1 = si[i], i2 = si[ixj];
            bool gt = (e1 > e2) || (e1 == e2 && i1 > i2);
            if (gt == up) { se[i] = e2; se[ixj] = e1; si[i] = i2; si[ixj] = i1; }
          }
        }
        __syncthreads();
      }
    seln = FILTER_K;
    for (int i = tid; i < FILTER_K; i += 256) sel[i] = si[i];
  }
  __syncthreads();
  // pad sel to a multiple of 32 with a valid index; padded rows get scale 0
  const int seln_pad = (seln + 31) & ~31;
  if (seln > 0)
    for (int i = seln + tid; i < seln_pad; i += 256) sel[i] = sel[0];
  __syncthreads();

  // lane owns dims [lane*8, lane*8+8); wave handles 8 rows per iteration
  float4 a0 = make_float4(0.f, 0.f, 0.f, 0.f), a1 = a0;
  for (int t = wid * 8; t < seln_pad; t += 32) {
    float4 u0[8], u1[8]; float s[8];
#pragma unroll
    for (int j = 0; j < 8; ++j) {
      int r = sel[t + j];
      const float4* p4 = (const float4*)((r < NN)
          ? supports_in + (size_t)r * DD : z + (size_t)(r - NN) * DD);
      u0[j] = p4[lane * 2]; u1[j] = p4[lane * 2 + 1];
    }
#pragma unroll
    for (int j = 0; j < 8; ++j)
      s[j] = u0[j].x * u0[j].x + u0[j].y * u0[j].y + u0[j].z * u0[j].z
           + u0[j].w * u0[j].w + u1[j].x * u1[j].x + u1[j].y * u1[j].y
           + u1[j].z * u1[j].z + u1[j].w * u1[j].w;
#pragma unroll
    for (int o = 1; o < 64; o <<= 1) {
#pragma unroll
      for (int j = 0; j < 8; ++j) s[j] += __shfl_xor(s[j], o, 64);
    }
#pragma unroll
    for (int j = 0; j < 8; ++j) {
      float sc = (t + j < seln) ? 1.0f / fmaxf(sqrtf(s[j]), 1e-12f) : 0.f;
      a0.x += u0[j].x * sc; a0.y += u0[j].y * sc;
      a0.z += u0[j].z * sc; a0.w += u0[j].w * sc;
      a1.x += u1[j].x * sc; a1.y += u1[j].y * sc;
      a1.z += u1[j].z * sc; a1.w += u1[j].w * sc;
    }
  }

  *(float4*)&part[wid][lane * 8] = a0;
  *(float4*)&part[wid][lane * 8 + 4] = a1;
  __syncthreads();
  const int d = tid * 2;
  float wx = part[0][d] + part[1][d] + part[2][d] + part[3][d];
  float wy = part[0][d + 1] + part[1][d + 1] + part[2][d + 1] + part[3][d + 1];
  float ss = wx * wx + wy * wy;
#pragma unroll
  for (int o = 1; o < 64; o <<= 1) ss += __shfl_xor(ss, o, 64);
  if (lane == 0) tot[wid] = ss;
  __syncthreads();
  float S = tot[0] + tot[1] + tot[2] + tot[3];
  float sc = 1.0f / fmaxf(sqrtf(S), 1e-12f);
  st_wc2(wn + (size_t)c * DD + 2 * tid, wx * sc, wy * sc);
}

// ---- shared 64x64 split-K A@B^T tile body (used by phases 3 and 6a) ----
// Cp[ks] += A[m0..m0+63][k0..k0+63] @ Bm[n0..n0+63][k0..k0+63]^T
__device__ __forceinline__ void gemm_abt_tile(
    const float* __restrict__ A, const float* __restrict__ Bm,
    float* __restrict__ Cb, float* smem, int tid, int m0, int n0, int k0) {
  float (*As)[68] = (float(*)[68])smem;
  float (*Bs)[68] = (float(*)[68])(smem + 16 * 68);
  const int ar = tid >> 2, ac = (tid & 3) * 4;
  const int tm = (tid >> 4) * 4, tn = (tid & 15) * 4;
  float acc[4][4] = {};
  float4 av = *(const float4*)&A[(size_t)(m0 + ar) * DD + k0 + ac];
  float4 bv = make_float4(0.f, 0.f, 0.f, 0.f);
  if (n0 + ar < CC) bv = *(const float4*)&Bm[(size_t)(n0 + ar) * DD + k0 + ac];
  for (int kk = 0; kk < 64; kk += 16) {
    __syncthreads();
    As[ac + 0][ar] = av.x; As[ac + 1][ar] = av.y;
    As[ac + 2][ar] = av.z; As[ac + 3][ar] = av.w;
    Bs[ac + 0][ar] = bv.x; Bs[ac + 1][ar] = bv.y;
    Bs[ac + 2][ar] = bv.z; Bs[ac + 3][ar] = bv.w;
    __syncthreads();
    if (kk + 16 < 64) {
      av = *(const float4*)&A[(size_t)(m0 + ar) * DD + k0 + kk + 16 + ac];
      if (n0 + ar < CC)
        bv = *(const float4*)&Bm[(size_t)(n0 + ar) * DD + k0 + kk + 16 + ac];
    }
#pragma unroll
    for (int q = 0; q < 16; ++q) {
      float4 a = *(const float4*)&As[q][tm];
      float4 b = *(const float4*)&Bs[q][tn];
      float aa[4] = {a.x, a.y, a.z, a.w};
      float bb[4] = {b.x, b.y, b.z, b.w};
#pragma unroll
      for (int i = 0; i < 4; ++i)
#pragma unroll
        for (int j = 0; j < 4; ++j) acc[i][j] += aa[i] * bb[j];
    }
  }
#pragma unroll
  for (int i = 0; i < 4; ++i) {
    int n = n0 + tn;
    if (n + 3 < CC) {
      st_wc4(&Cb[(size_t)(m0 + tm + i) * CC + n],
             make_float4(acc[i][0], acc[i][1], acc[i][2], acc[i][3]));
    } else {
#pragma unroll
      for (int j = 0; j < 4; ++j)
        if (n + j < CC) st_wc1(&Cb[(size_t)(m0 + tm + i) * CC + n + j], acc[i][j]);
    }
  }
}

// =================== the persistent mega-kernel ===================
__global__ __launch_bounds__(256, 2) void mega(
    const float* x, const float* Wf, const float* Wc, const float* bc,
    const float* supports_in, const float* ent_in, const int* labels_idx,
    float* out, float* ws) {
  __shared__ __align__(16) float smem[SMEM_F];
  float*  z     = ws + Z_OFF;
  int*    cnt   = (int*)(ws + CNT_OFF);
  float2* ei    = (float2*)(ws + EI_OFF);
  float*  wn    = ws + WN_OFF;
  float*  zpart = ws + ZP_OFF;
  float*  ppart = ws + PP_OFF;
  float*  opart = ws + OP_OFF;
  const int bid = blockIdx.x, tid = threadIdx.x;
  const int grp = bid >> 6;            // 8 groups of 64 blocks

  // ---- Phase 1: zpart = x@Wf split-K, ALL 512 blocks (SK1=32, klen=64) ----
  {
    float (*As)[68]  = (float(*)[68])smem;
    float (*Bs)[132] = (float(*)[132])(smem + 16 * 68);
    const int m0 = ((bid >> 2) & 3) * 64;
    const int n0 = (bid & 3) * 128;
    const int k0 = (bid >> 4) * 64;
    const int ar = tid >> 2, ac = (tid & 3) * 4;
    const int br = tid >> 4, bcn = (tid & 15) * 8;
    const int tm = (tid >> 4) * 4, tn = (tid & 15) * 4;
    float acc[4][8] = {};
    float4 av  = *(const float4*)&x[(size_t)(m0 + ar) * DIN + k0 + ac];
    float4 bv0 = *(const float4*)&Wf[(size_t)(k0 + br) * DD + n0 + bcn];
    float4 bv1 = *(const float4*)&Wf[(size_t)(k0 + br) * DD + n0 + bcn + 4];
    for (int kk = 0; kk < 64; kk += 16) {
      __syncthreads();
      As[ac + 0][ar] = av.x; As[ac + 1][ar] = av.y;
      As[ac + 2][ar] = av.z; As[ac + 3][ar] = av.w;
      *(float4*)&Bs[br][bcn] = bv0;
      *(float4*)&Bs[br][bcn + 4] = bv1;
      __syncthreads();
      if (kk + 16 < 64) {   // register prefetch of next K-tile
        av  = *(const float4*)&x[(size_t)(m0 + ar) * DIN + k0 + kk + 16 + ac];
        bv0 = *(const float4*)&Wf[(size_t)(k0 + kk + 16 + br) * DD + n0 + bcn];
        bv1 = *(const float4*)&Wf[(size_t)(k0 + kk + 16 + br) * DD + n0 + bcn + 4];
      }
#pragma unroll
      for (int q = 0; q < 16; ++q) {
        float4 a  = *(const float4*)&As[q][tm];
        float4 b0 = *(const float4*)&Bs[q][tn];
        float4 b1 = *(const float4*)&Bs[q][tn + 64];
        float aa[4] = {a.x, a.y, a.z, a.w};
        float bb[8] = {b0.x, b0.y, b0.z, b0.w, b1.x, b1.y, b1.z, b1.w};
#pragma unroll
        for (int i = 0; i < 4; ++i)
#pragma unroll
          for (int j = 0; j < 8; ++j) acc[i][j] += aa[i] * bb[j];
      }
    }
    float* Cb = zpart + (size_t)(bid >> 4) * BB * DD;
#pragma unroll
    for (int i = 0; i < 4; ++i) {
      st_wc4(&Cb[(size_t)(m0 + tm + i) * DD + n0 + tn],
             make_float4(acc[i][0], acc[i][1], acc[i][2], acc[i][3]));
      st_wc4(&Cb[(size_t)(m0 + tm + i) * DD + n0 + 64 + tn],
             make_float4(acc[i][4], acc[i][5], acc[i][6], acc[i][7]));
    }
  }
  gsync(cnt, 1, grp);

  // ---- Phase 2: z = sum of 32 partials (blocks 0..127) | old-row scatter
  // ---- (blocks 128..323); remaining blocks idle through the barrier. ----
  if (bid < 128) {
    const int n4 = BB * DD / 4;
    int i = bid * 256 + tid;
    if (i < n4) {
      const float4* p4 = (const float4*)zpart;
      float4 a = p4[i];
#pragma unroll
      for (int s = 1; s < SK1; ++s) {
        float4 b = p4[(size_t)s * n4 + i];
        a.x += b.x; a.y += b.y; a.z += b.z; a.w += b.w;
      }
      st_wc4(z + 4 * (size_t)i, a);
    }
  } else if (bid < 324) {
    int m = (bid - 128) * 256 + tid;
    if (m < NN) {
      int c = labels_idx[m];
      int pos = atomicAdd(&cnt[c * CSTRIDE], 1);
      if (pos < SLOT) {
        st_wc2((float*)&ei[(size_t)c * SLOT + pos], ent_in[m], __int_as_float(m));
      }
    }
  }
  gsync(cnt, 2, grp);

  // ---- Phase 3: ppart[s] = z @ Wc^T (512 blocks; 64x64 tile, klen 64) ----
  {
    const int ks = bid >> 6;            // 0..7
    gemm_abt_tile(z, Wc, ppart + (size_t)ks * BB * CC, smem, tid,
                  ((bid >> 4) & 3) * 64, (bid & 15) * 64, ks * 64);
  }
  gsync(cnt, 3, grp);

  // ---- Phase 4: rowstats — argmax+entropy over p partials; new-row scatter ----
  if (bid < BB) {
    float* smv = smem; int* smi = (int*)(smem + 4);
    float* ssm = smem + 8; float* tsm = smem + 12;
    const int b = bid;
    const int lane = tid & 63, wid = tid >> 6;
    const int cbase = tid * 4;          // thread owns 4 consecutive cols
    float rr[4];
    float mv = -INFINITY; int mi = 0x7fffffff;
    if (cbase < CC) {
      float4 v = *(const float4*)&bc[cbase];
#pragma unroll
      for (int s = 0; s < SKP; ++s) {
        float4 pv = *(const float4*)&ppart[(size_t)s * BB * CC + (size_t)b * CC + cbase];
        v.x += pv.x; v.y += pv.y; v.z += pv.z; v.w += pv.w;
      }
      rr[0] = v.x; rr[1] = v.y; rr[2] = v.z; rr[3] = v.w;
#pragma unroll
      for (int j = 0; j < 4; ++j)
        if (rr[j] > mv) { mv = rr[j]; mi = cbase + j; }   // ascending keeps first
    } else { rr[0] = rr[1] = rr[2] = rr[3] = -INFINITY; }
#pragma unroll
    for (int o = 32; o > 0; o >>= 1) {
      float ov = __shfl_down(mv, o, 64);
      int oi = __shfl_down(mi, o, 64);
      if (ov > mv || (ov == mv && oi < mi)) { mv = ov; mi = oi; }
    }
    if (lane == 0) { smv[wid] = mv; smi[wid] = mi; }
    __syncthreads();
    if (tid == 0) {
#pragma unroll
      for (int w = 1; w < 4; ++w)
        if (smv[w] > smv[0] || (smv[w] == smv[0] && smi[w] < smi[0])) {
          smv[0] = smv[w]; smi[0] = smi[w];
        }
    }
    __syncthreads();
    const float m = smv[0]; const int am = smi[0];
    float s = 0.f, t = 0.f;
    if (cbase < CC) {
#pragma unroll
      for (int j = 0; j < 4; ++j) {
        float u = rr[j] - m;
        float e = expf(u);
        s += e; t += u * e;
      }
    }
#pragma unroll
    for (int o = 32; o > 0; o >>= 1) {
      s += __shfl_down(s, o, 64);
      t += __shfl_down(t, o, 64);
    }
    if (lane == 0) { ssm[wid] = s; tsm[wid] = t; }
    __syncthreads();
    if (tid == 0) {
      float S = ssm[0] + ssm[1] + ssm[2] + ssm[3];
      float T = tsm[0] + tsm[1] + tsm[2] + tsm[3];
      float ent = logf(S) - T / S;
      int pos = atomicAdd(&cnt[am * CSTRIDE], 1);
      if (pos < SLOT) {
        st_wc2((float*)&ei[(size_t)am * SLOT + pos], ent, __int_as_float(NN + b));
      }
    }
  }
  gsync(cnt, 4, grp);

  // ---- Phase 5: class weights (each block: class bid, then bid+512) ----
  do_class(bid, tid, smem, supports_in, z, ei, cnt, wn);
  __syncthreads();
  if (bid + 512 < CC)
    do_class(bid + 512, tid, smem, supports_in, z, ei, cnt, wn);
  gsync(cnt, 5, grp);

  // ---- Phase 6a: opart[s] = z @ wn^T (512 blocks; same shape as phase 3) ----
  {
    const int ks = bid >> 6;            // 0..7
    gemm_abt_tile(z, wn, opart + (size_t)ks * BB * CC, smem, tid,
                  ((bid >> 4) & 3) * 64, (bid & 15) * 64, ks * 64);
  }
  gsync(cnt, 6, grp);

  // ---- Phase 6b: out = sum of 8 opart partials (blocks 0..255) ----
  if (bid < 256) {
    const int cbase = tid * 4;          // 1000/4 = 250 threads active
    if (cbase < CC) {
      float4 a = *(const float4*)&opart[(size_t)bid * CC + cbase];
#pragma unroll
      for (int s = 1; s < SKO; ++s) {
        float4 b = *(const float4*)&opart[(size_t)s * BB * CC + (size_t)bid * CC + cbase];
        a.x += b.x; a.y += b.y; a.z += b.z; a.w += b.w;
      }
      *(float4*)&out[(size_t)bid * CC + cbase] = a;   // final output: normal store
    }
  }
}

// ============================ launcher ===================================
extern "C" void kernel_launch(void* const* d_in, const int* in_sizes, int n_in,
                              void* d_out, int out_size, void* d_ws, size_t ws_size,
                              hipStream_t stream) {
  (void)in_sizes; (void)n_in; (void)out_size; (void)ws_size;
  const float* x           = (const float*)d_in[0];
  const float* Wf          = (const float*)d_in[1];
  const float* Wc          = (const float*)d_in[2];
  const float* bc          = (const float*)d_in[3];
  const float* supports_in = (const float*)d_in[4];
  const float* ent_in      = (const float*)d_in[5];
  const int*   labels_idx  = (const int*)d_in[6];
  float* out = (float*)d_out;
  float* W = (float*)d_ws;
  int* cnt = (int*)(W + CNT_OFF);

  // zero class counters + barrier words (64 KB, covers idx 0..16383)
  hipMemsetAsync(cnt, 0, 1024 * CSTRIDE * sizeof(int), stream);
  // single persistent kernel; 512 blocks = 2/CU guaranteed resident
  hipLaunchKernelGGL(mega, dim3(NBLK), dim3(256), 0, stream,
                     x, Wf, Wc, bc, supports_in, ent_in, labels_idx, out, W);
}